// Round 1
// 332.464 us; speedup vs baseline: 1.0454x; 1.0454x over previous
//
#include <hip/hip_runtime.h>
#include <math.h>

#define BATCH 16
#define HF 1024
#define WF 1024
#define HS 512
#define WS2 512
#define HC 256
#define WC 256
#define KMAX 32
#define CAP 16384
#define CROPSZ 160
#define CNT_STRIDE 16
#define NCHUNK 16
#define CHUNK 1024

// ---- workspace byte offsets ----
#define OFF_IMGS 0UL                                   // 16*512*512 f32 = 16 MB
#define OFF_CMS  16777216UL                            // 16*256*256 f32 = 4 MB
#define OFF_KEYS 20971520UL                            // 16*16384 u64  = 2 MB
#define OFF_CNT  23068672UL                            // 16*16 int
#define OFF_CX   23070720UL                            // 512 f32
#define OFF_CY   (OFF_CX + 2048UL)
#define OFF_VLD  (OFF_CY + 2048UL)
#define OFF_CAND (OFF_VLD + 2048UL)                    // 16*16*32 u64 = 64 KB

// ---- output element offsets ----
#define OUT_CROPS 0
#define OUT_OFFS  13107200
#define OUT_VALS  13108224
#define OUT_VALID 13108736

// jax.image.resize(bilinear, antialias) at 0.5: 4-tap {1,3,3,1}/8, edge-renorm.
// Block = one output row (2 px/thread); the 4 source rows staged in LDS via
// coalesced float4 loads. Also resets the peak counters (block (0,0)).
__global__ __launch_bounds__(256) void resize_kernel(const float* __restrict__ full,
                                                     float* __restrict__ imgs,
                                                     int* __restrict__ counts) {
    if (blockIdx.x == 0 && blockIdx.y == 0 && threadIdx.x < BATCH * CNT_STRIDE)
        counts[threadIdx.x] = 0;
    __shared__ float simg[4][1024];
    int tid = threadIdx.x;
    int y = blockIdx.x;          // 0..511
    int b = blockIdx.y;
    const float w4[4] = {0.125f, 0.375f, 0.375f, 0.125f};
    float wy[4];
    int ry[4];
    float sy = 0.f;
#pragma unroll
    for (int j = 0; j < 4; ++j) {
        int r = 2 * y - 1 + j;
        float w = (r >= 0 && r < HF) ? w4[j] : 0.f;
        wy[j] = w; sy += w;
        ry[j] = r < 0 ? 0 : (r >= HF ? HF - 1 : r);
    }
    const float* base = full + ((size_t)b << 20);
#pragma unroll
    for (int j = 0; j < 4; ++j) {
        const float4* rp4 = (const float4*)(base + ry[j] * WF);
        ((float4*)simg[j])[tid] = rp4[tid];
    }
    __syncthreads();
#pragma unroll
    for (int p = 0; p < 2; ++p) {
        int x = tid + 256 * p;
        float wx[4];
        int rx[4];
        float sx = 0.f;
#pragma unroll
        for (int ii = 0; ii < 4; ++ii) {
            int c = 2 * x - 1 + ii;
            float wc = (c >= 0 && c < WF) ? w4[ii] : 0.f;
            wx[ii] = wc; sx += wc;
            rx[ii] = c < 0 ? 0 : (c >= WF ? WF - 1 : c);
        }
        float inv = 1.f / (sy * sx);
        float acc = 0.f;
#pragma unroll
        for (int j = 0; j < 4; ++j) {
            float rowacc = 0.f;
#pragma unroll
            for (int ii = 0; ii < 4; ++ii) rowacc += wx[ii] * simg[j][rx[ii]];
            acc += wy[j] * rowacc;
        }
        imgs[((size_t)b << 18) + (y << 9) + x] = acc * inv;
    }
}

// Fused conv1(5x5 s2, 1->32, relu) + conv2(5x5 s1, 32->1, sigmoid).
// One block = 32x32 cms output tile. The 128 MB h intermediate never touches
// HBM: stage the 75x75 imgs tile in LDS once, then stream 8 channel-quads —
// per quad, compute the 36x36 h tile (float4 = 4 ch) into LDS and immediately
// accumulate its conv2 partial into per-thread registers, reusing the same
// LDS buffer. Per-quad w1/w2 weights live in 25 float4 registers (statically
// indexed). conv2 stage: thread = (col cx, 4 rows), 8 h-rows walked once with
// vertical register reuse (40 ds_read_b128/thread/quad instead of 100).
// OOB h rows/cols are zeroed (== conv2 SAME zero-padding exactly); OOB imgs
// in the staged tile are zeroed (== conv1 SAME zero-padding exactly).
__global__ __launch_bounds__(256) void conv_fused2_kernel(
    const float* __restrict__ imgs, const float* __restrict__ w1,
    const float* __restrict__ b1, const float* __restrict__ w2,
    const float* __restrict__ b2, float* __restrict__ cms) {
    __shared__ float simg[75][76];     // imgs tile [2Y0-5 .. 2Y0+69]
    __shared__ float4 sh[36][37];      // h quad tile, rows Y0-2 .. Y0+33
    int tid = threadIdx.x;
    int b = blockIdx.y;
    int Y0 = (blockIdx.x >> 3) << 5;   // 8x8 tiles of 32x32
    int X0 = (blockIdx.x & 7) << 5;

    // ---- stage imgs tile (zero outside image == conv1 zero-pad) ----
    const float* ib = imgs + ((size_t)b << 18);
    int r0 = 2 * Y0 - 5, c0 = 2 * X0 - 5;
    for (int i = tid; i < 75 * 76; i += 256) {
        int r = i / 76, c = i - r * 76;
        int gy = r0 + r, gx = c0 + c;
        float v = 0.f;
        if ((unsigned)gy < 512u && (unsigned)gx < 512u)
            v = ib[(gy << 9) + gx];
        simg[r][c] = v;
    }

    int cx = tid & 31;                 // output column within tile
    int ry0 = (tid >> 5) << 2;         // output rows ry0..ry0+3
    float bb = b2[0];
    float z0 = bb, z1 = bb, z2 = bb, z3 = bb;

    for (int q = 0; q < 8; ++q) {
        // w1 quad into registers: w1[(ky*5+kx)*32 + 4q + 0..3]
        float4 wq[25];
        const float4* w1q = (const float4*)(w1 + 4 * q);
#pragma unroll
        for (int t = 0; t < 25; ++t) wq[t] = w1q[t * 8];
        float4 bq = *(const float4*)(b1 + 4 * q);

        // q==0: wait for simg staging; q>0: wait for prev conv2 reads of sh
        __syncthreads();

        // ---- h quad tile: 36x36 pixels, 4 channels each ----
#pragma unroll
        for (int it = 0; it < 6; ++it) {
            int p = tid + (it << 8);
            if (p < 1296) {
                int hy = p / 36;
                int hx = p - hy * 36;
                float4 acc = make_float4(0.f, 0.f, 0.f, 0.f);
                int gy = Y0 - 2 + hy, gx = X0 - 2 + hx;
                if ((unsigned)gy < 256u && (unsigned)gx < 256u) {
                    acc = bq;
                    // conv1 window for h row gy: simg rows 2hy..2hy+4
                    const float* sp = &simg[2 * hy][2 * hx];
#pragma unroll
                    for (int ky = 0; ky < 5; ++ky)
#pragma unroll
                        for (int kx = 0; kx < 5; ++kx) {
                            float v = sp[ky * 76 + kx];
                            float4 w = wq[ky * 5 + kx];
                            acc.x += v * w.x; acc.y += v * w.y;
                            acc.z += v * w.z; acc.w += v * w.w;
                        }
                    acc.x = fmaxf(acc.x, 0.f); acc.y = fmaxf(acc.y, 0.f);
                    acc.z = fmaxf(acc.z, 0.f); acc.w = fmaxf(acc.w, 0.f);
                }
                sh[hy][hx] = acc;
            }
        }

        // w2 quad into the same registers (independent of LDS, so before sync)
        const float4* w2q = (const float4*)(w2 + 4 * q);
#pragma unroll
        for (int t = 0; t < 25; ++t) wq[t] = w2q[t * 8];

        __syncthreads();

        // ---- conv2 partial: 4 outputs/thread, vertical register reuse ----
        // output row ry0+j uses h tile rows ry0+j .. ry0+j+4 (ky = rr - j)
#pragma unroll
        for (int rr = 0; rr < 8; ++rr) {
#pragma unroll
            for (int kx = 0; kx < 5; ++kx) {
                float4 hv = sh[ry0 + rr][cx + kx];
#pragma unroll
                for (int j = 0; j < 4; ++j) {
                    int ky = rr - j;
                    if (ky < 0 || ky > 4) continue;
                    float4 w = wq[ky * 5 + kx];
                    float d = hv.x * w.x + hv.y * w.y + hv.z * w.z + hv.w * w.w;
                    if (j == 0) z0 += d;
                    else if (j == 1) z1 += d;
                    else if (j == 2) z2 += d;
                    else z3 += d;
                }
            }
        }
    }

    size_t ob = ((size_t)b << 16) + ((size_t)(Y0 + ry0) << 8) + (X0 + cx);
    cms[ob]       = 1.f / (1.f + expf(-z0));
    cms[ob + 256] = 1.f / (1.f + expf(-z1));
    cms[ob + 512] = 1.f / (1.f + expf(-z2));
    cms[ob + 768] = 1.f / (1.f + expf(-z3));
}

// 3x3 NMS + threshold; LDS staging, one global atomic per row-block.
__global__ __launch_bounds__(256) void peak_scan_kernel(
    const float* __restrict__ cms, unsigned long long* __restrict__ keys,
    int* __restrict__ counts) {
    int b = blockIdx.x >> 8;
    int y = blockIdx.x & 255;
    int x = threadIdx.x;
    const float* cb = cms + ((size_t)b << 16);
    __shared__ float rows[3][256];
    __shared__ int lcnt, lbase;
    if (x == 0) lcnt = 0;
#pragma unroll
    for (int j = 0; j < 3; ++j) {
        int yy = y - 1 + j;
        rows[j][x] = (yy >= 0 && yy < HC) ? cb[yy * WC + x] : -INFINITY;
    }
    __syncthreads();
    float c = rows[1][x];
    bool peak = (c > 0.2f);
    if (peak) {
#pragma unroll
        for (int j = 0; j < 3; ++j) {
            float r0 = rows[j][x];
            float rl = (x > 0)   ? rows[j][x - 1] : -INFINITY;
            float rr = (x < 255) ? rows[j][x + 1] : -INFINITY;
            if (fmaxf(r0, fmaxf(rl, rr)) > c) peak = false;
        }
    }
    int p = -1;
    if (peak) p = atomicAdd(&lcnt, 1);
    __syncthreads();
    if (x == 0) lbase = lcnt ? atomicAdd(&counts[b * CNT_STRIDE], lcnt) : 0;
    __syncthreads();
    if (peak) {
        int pos = lbase + p;
        if (pos < CAP) {
            int i = y * WC + x;
            unsigned long long key =
                ((unsigned long long)__float_as_uint(c) << 32) |
                (unsigned long long)(0xFFFFFFFFu - (unsigned)i);
            keys[(size_t)b * CAP + pos] = key;
        }
    }
}

// Stage A: per (batch, chunk-of-1024) exact top-32 with removal, in LDS.
__global__ __launch_bounds__(256) void topk_stage_a(
    const unsigned long long* __restrict__ keys, const int* __restrict__ counts,
    unsigned long long* __restrict__ cand) {
    int b = blockIdx.x >> 4;
    int chunk = blockIdx.x & 15;
    int tid = threadIdx.x;
    __shared__ unsigned long long lk[CHUNK];
    __shared__ unsigned long long rkey[256];
    __shared__ int rpos[256];
    int cnt = counts[b * CNT_STRIDE]; if (cnt > CAP) cnt = CAP;
    const unsigned long long* kb = keys + (size_t)b * CAP + chunk * CHUNK;
    int lim = cnt - chunk * CHUNK;
#pragma unroll
    for (int k = 0; k < 4; ++k) {
        int i = tid + k * 256;
        lk[i] = (i < lim) ? kb[i] : 0ULL;
    }
    __syncthreads();
    unsigned long long* out = cand + (size_t)(b * NCHUNK + chunk) * KMAX;
    for (int k = 0; k < KMAX; ++k) {
        unsigned long long best = 0ULL; int bp = -1;
#pragma unroll
        for (int j = 0; j < 4; ++j) {
            int i = tid + j * 256;
            unsigned long long kk = lk[i];
            if (kk > best) { best = kk; bp = i; }
        }
        rkey[tid] = best; rpos[tid] = bp;
        __syncthreads();
        for (int s = 128; s > 0; s >>= 1) {
            if (tid < s && rkey[tid + s] > rkey[tid]) {
                rkey[tid] = rkey[tid + s]; rpos[tid] = rpos[tid + s];
            }
            __syncthreads();
        }
        unsigned long long w = rkey[0];
        if (w == 0ULL) {
            if (tid >= k && tid < KMAX) out[tid] = 0ULL;
            break;
        }
        if (tid == 0) { out[k] = w; lk[rpos[0]] = 0ULL; }
        __syncthreads();
    }
}

// Stage B: per batch, exact top-32 over 512 candidates + integral refinement.
__global__ __launch_bounds__(256) void topk_stage_b(
    const float* __restrict__ cms, const unsigned long long* __restrict__ cand,
    float* __restrict__ out_off, float* __restrict__ out_vals,
    float* __restrict__ out_valid, float* __restrict__ ws_cx,
    float* __restrict__ ws_cy, float* __restrict__ ws_v) {
    int b = blockIdx.x;
    int tid = threadIdx.x;
    __shared__ unsigned long long lk[NCHUNK * KMAX];   // 512
    __shared__ unsigned long long rkey[256];
    __shared__ int rpos[256];
    __shared__ unsigned long long sel[KMAX];
    lk[tid]       = cand[(size_t)b * 512 + tid];
    lk[tid + 256] = cand[(size_t)b * 512 + 256 + tid];
    if (tid < KMAX) sel[tid] = 0ULL;
    __syncthreads();
    for (int k = 0; k < KMAX; ++k) {
        unsigned long long best = 0ULL; int bp = -1;
        {
            unsigned long long k0 = lk[tid], k1 = lk[tid + 256];
            if (k0 > best) { best = k0; bp = tid; }
            if (k1 > best) { best = k1; bp = tid + 256; }
        }
        rkey[tid] = best; rpos[tid] = bp;
        __syncthreads();
        for (int s = 128; s > 0; s >>= 1) {
            if (tid < s && rkey[tid + s] > rkey[tid]) {
                rkey[tid] = rkey[tid + s]; rpos[tid] = rpos[tid + s];
            }
            __syncthreads();
        }
        unsigned long long w = rkey[0];
        if (w == 0ULL) break;
        if (tid == 0) { sel[k] = w; lk[rpos[0]] = 0ULL; }
        __syncthreads();
    }
    __syncthreads();
    if (tid < KMAX) {
        int k = tid;
        unsigned long long key = sel[k];
        bool valid = key != 0ULL;
        float cx = 80.f, cy = 80.f, val = 0.f;
        if (valid) {
            val = __uint_as_float((unsigned)(key >> 32));
            int idx = (int)(0xFFFFFFFFu - (unsigned)(key & 0xFFFFFFFFULL));
            int py = idx >> 8, px = idx & 255;
            const float* cb = cms + ((size_t)b << 16);
            float gv = 1e-12f, sdx = 0.f, sdy = 0.f;
#pragma unroll
            for (int oy = -2; oy <= 2; ++oy)
#pragma unroll
                for (int ox = -2; ox <= 2; ++ox) {
                    int yy = py + oy, xx = px + ox;
                    if (yy < 0 || yy >= HC || xx < 0 || xx >= WC) continue;
                    float pv = cb[yy * WC + xx];
                    gv += pv; sdx += pv * (float)ox; sdy += pv * (float)oy;
                }
            float dx = sdx / gv, dy = sdy / gv;
            cx = ((float)px + dx) * 4.f;
            cy = ((float)py + dy) * 4.f;
        }
        int o = b * KMAX + k;
        out_off[o * 2 + 0] = cx - 80.f;
        out_off[o * 2 + 1] = cy - 80.f;
        out_vals[o] = val;
        out_valid[o] = valid ? 1.f : 0.f;
        ws_cx[o] = cx; ws_cy[o] = cy; ws_v[o] = valid ? 1.f : 0.f;
    }
}

__global__ __launch_bounds__(256) void crop_kernel(
    const float* __restrict__ full, const float* __restrict__ ws_cx,
    const float* __restrict__ ws_cy, const float* __restrict__ ws_v,
    float* __restrict__ out_crops) {
    int bidx = blockIdx.x;
    int cid = bidx / 100;
    int pp = (bidx - cid * 100) * 256 + threadIdx.x;
    int b = cid >> 5;
    float cx = ws_cx[cid], cy = ws_cy[cid], v = ws_v[cid];
    int row = pp / CROPSZ, col = pp - row * CROPSZ;
    float sy = cy - 79.5f + (float)row;
    float sx = cx - 79.5f + (float)col;
    float y0f = floorf(sy), x0f = floorf(sx);
    float wy = sy - y0f, wx = sx - x0f;
    int y0 = (int)y0f, x0 = (int)x0f;
    int yi0 = min(max(y0, 0), HF - 1);
    int yi1 = min(max(y0 + 1, 0), HF - 1);
    int xi0 = min(max(x0, 0), WF - 1);
    int xi1 = min(max(x0 + 1, 0), WF - 1);
    const float* base = full + ((size_t)b << 20);
    float t00 = base[yi0 * WF + xi0];
    float t01 = base[yi0 * WF + xi1];
    float t10 = base[yi1 * WF + xi0];
    float t11 = base[yi1 * WF + xi1];
    float top = t00 * (1.f - wx) + t01 * wx;
    float bot = t10 * (1.f - wx) + t11 * wx;
    float val = top * (1.f - wy) + bot * wy;
    float inr = (sy >= 0.f && sy <= (float)(HF - 1) &&
                 sx >= 0.f && sx <= (float)(WF - 1)) ? 1.f : 0.f;
    out_crops[(size_t)cid * (CROPSZ * CROPSZ) + pp] = val * inr * v;
}

extern "C" void kernel_launch(void* const* d_in, const int* in_sizes, int n_in,
                              void* d_out, int out_size, void* d_ws, size_t ws_size,
                              hipStream_t stream) {
    const float* full = (const float*)d_in[0];
    const float* w1   = (const float*)d_in[1];
    const float* b1   = (const float*)d_in[2];
    const float* w2   = (const float*)d_in[3];
    const float* b2   = (const float*)d_in[4];

    char* ws = (char*)d_ws;
    float* imgs = (float*)(ws + OFF_IMGS);
    float* cms  = (float*)(ws + OFF_CMS);
    unsigned long long* keys = (unsigned long long*)(ws + OFF_KEYS);
    int* counts = (int*)(ws + OFF_CNT);
    float* ws_cx = (float*)(ws + OFF_CX);
    float* ws_cy = (float*)(ws + OFF_CY);
    float* ws_v  = (float*)(ws + OFF_VLD);
    unsigned long long* cand = (unsigned long long*)(ws + OFF_CAND);

    float* out = (float*)d_out;
    float* out_crops = out + OUT_CROPS;
    float* out_off   = out + OUT_OFFS;
    float* out_vals  = out + OUT_VALS;
    float* out_valid = out + OUT_VALID;

    hipLaunchKernelGGL(resize_kernel, dim3(512, 16), dim3(256), 0, stream,
                       full, imgs, counts);

    hipLaunchKernelGGL(conv_fused2_kernel, dim3(64, 16), dim3(256), 0, stream,
                       imgs, w1, b1, w2, b2, cms);

    hipLaunchKernelGGL(peak_scan_kernel, dim3(4096), dim3(256), 0, stream,
                       cms, keys, counts);
    hipLaunchKernelGGL(topk_stage_a, dim3(256), dim3(256), 0, stream,
                       keys, counts, cand);
    hipLaunchKernelGGL(topk_stage_b, dim3(16), dim3(256), 0, stream,
                       cms, cand, out_off, out_vals, out_valid,
                       ws_cx, ws_cy, ws_v);
    hipLaunchKernelGGL(crop_kernel, dim3(51200), dim3(256), 0, stream,
                       full, ws_cx, ws_cy, ws_v, out_crops);
}

// Round 2
// 323.714 us; speedup vs baseline: 1.0737x; 1.0270x over previous
//
#include <hip/hip_runtime.h>
#include <math.h>

#define BATCH 16
#define HF 1024
#define WF 1024
#define HS 512
#define WS2 512
#define HC 256
#define WC 256
#define KMAX 32
#define CAP 16384
#define CROPSZ 160
#define CNT_STRIDE 16
#define NCHUNK 16
#define CHUNK 1024

// ---- workspace byte offsets ----
#define OFF_IMGS 0UL                                   // 16*512*512 f32 = 16 MB
#define OFF_CMS  16777216UL                            // 16*256*256 f32 = 4 MB
#define OFF_KEYS 20971520UL                            // 16*16384 u64  = 2 MB
#define OFF_CNT  23068672UL                            // 16*16 int
#define OFF_CX   23070720UL                            // 512 f32
#define OFF_CY   (OFF_CX + 2048UL)
#define OFF_VLD  (OFF_CY + 2048UL)
#define OFF_CAND (OFF_VLD + 2048UL)                    // 16*16*32 u64 = 64 KB

// ---- output element offsets ----
#define OUT_CROPS 0
#define OUT_OFFS  13107200
#define OUT_VALS  13108224
#define OUT_VALID 13108736

// jax.image.resize(bilinear, antialias) at 0.5: 4-tap {1,3,3,1}/8, edge-renorm.
__global__ __launch_bounds__(256) void resize_kernel(const float* __restrict__ full,
                                                     float* __restrict__ imgs,
                                                     int* __restrict__ counts) {
    if (blockIdx.x == 0 && blockIdx.y == 0 && threadIdx.x < BATCH * CNT_STRIDE)
        counts[threadIdx.x] = 0;
    __shared__ float simg[4][1024];
    int tid = threadIdx.x;
    int y = blockIdx.x;          // 0..511
    int b = blockIdx.y;
    const float w4[4] = {0.125f, 0.375f, 0.375f, 0.125f};
    float wy[4];
    int ry[4];
    float sy = 0.f;
#pragma unroll
    for (int j = 0; j < 4; ++j) {
        int r = 2 * y - 1 + j;
        float w = (r >= 0 && r < HF) ? w4[j] : 0.f;
        wy[j] = w; sy += w;
        ry[j] = r < 0 ? 0 : (r >= HF ? HF - 1 : r);
    }
    const float* base = full + ((size_t)b << 20);
#pragma unroll
    for (int j = 0; j < 4; ++j) {
        const float4* rp4 = (const float4*)(base + ry[j] * WF);
        ((float4*)simg[j])[tid] = rp4[tid];
    }
    __syncthreads();
#pragma unroll
    for (int p = 0; p < 2; ++p) {
        int x = tid + 256 * p;
        float wx[4];
        int rx[4];
        float sx = 0.f;
#pragma unroll
        for (int ii = 0; ii < 4; ++ii) {
            int c = 2 * x - 1 + ii;
            float wc = (c >= 0 && c < WF) ? w4[ii] : 0.f;
            wx[ii] = wc; sx += wc;
            rx[ii] = c < 0 ? 0 : (c >= WF ? WF - 1 : c);
        }
        float inv = 1.f / (sy * sx);
        float acc = 0.f;
#pragma unroll
        for (int j = 0; j < 4; ++j) {
            float rowacc = 0.f;
#pragma unroll
            for (int ii = 0; ii < 4; ++ii) rowacc += wx[ii] * simg[j][rx[ii]];
            acc += wy[j] * rowacc;
        }
        imgs[((size_t)b << 18) + (y << 9) + x] = acc * inv;
    }
}

// Fused conv1(5x5 s2, 1->32, relu) + conv2(5x5 s1, 32->1, sigmoid).
// Block = 32x32 cms tile; stream 8 channel-quads through one LDS h buffer.
// R2: conv1 restructured from 25 scalar stride-2 ds_read_b32 per h-pixel
// (even-banks-only -> 4-way conflict, LDS-pipe-bound at ~87us/CU) to
// 6-pixel horizontal groups reading 5 rows x 4 ds_read_b128 (contiguous
// bank pattern, 3.3x fewer LDS instructions). Work assignment + all LDS
// base addresses hoisted out of the quad loop (no per-quad int division).
// Weights load via uniform float4 index -> scalarized to SGPRs (R1: V68/S112).
__global__ __launch_bounds__(256) void conv_fused2_kernel(
    const float* __restrict__ imgs, const float* __restrict__ w1,
    const float* __restrict__ b1, const float* __restrict__ w2,
    const float* __restrict__ b2, float* __restrict__ cms) {
    __shared__ float simg[75][76];     // imgs tile [2Y0-5 .. 2Y0+69]
    __shared__ float4 sh[36][37];      // h quad tile, rows Y0-2 .. Y0+33
    int tid = threadIdx.x;
    int b = blockIdx.y;
    int Y0 = (blockIdx.x >> 3) << 5;   // 8x8 tiles of 32x32
    int X0 = (blockIdx.x & 7) << 5;

    // ---- stage imgs tile (zero outside image == conv1 zero-pad) ----
    const float* ib = imgs + ((size_t)b << 18);
    int r0 = 2 * Y0 - 5, c0 = 2 * X0 - 5;
    for (int i = tid; i < 75 * 76; i += 256) {
        int r = i / 76, c = i - r * 76;
        int gy = r0 + r, gx = c0 + c;
        float v = 0.f;
        if ((unsigned)gy < 512u && (unsigned)gx < 512u)
            v = ib[(gy << 9) + gx];
        simg[r][c] = v;
    }

    // ---- conv1 work assignment (hoisted; quad-invariant) ----
    // group = 6 horizontal h-pixels: 6 groups/row * 36 rows = 216 groups.
    bool c1act = tid < 216;
    int ghy = tid / 6;                         // 0..35 (one div, outside loop)
    int ghx0 = (tid - ghy * 6) * 6;            // 0,6,..,30
    const float* c1base = &simg[2 * ghy][2 * ghx0];  // 16B-aligned (2ghx0 %4==0)
    float4* shw = &sh[ghy][ghx0];
    bool rowok = (unsigned)(Y0 - 2 + ghy) < 256u;
    int gx0 = X0 - 2 + ghx0;

    // ---- conv2 work assignment (hoisted) ----
    int cx = tid & 31;                 // output column within tile
    int ry0 = (tid >> 5) << 2;         // output rows ry0..ry0+3
    const float4* hb = &sh[ry0][cx];   // all 40 reads = hb[rr*37 + kx]
    float bb = b2[0];
    float z0 = bb, z1 = bb, z2 = bb, z3 = bb;

    for (int q = 0; q < 8; ++q) {
        // w1 quad: uniform loads -> SGPRs. wq[t] = float4(ch 4q..4q+3, tap t)
        float4 wq[25];
        const float4* w14 = (const float4*)w1;
#pragma unroll
        for (int t = 0; t < 25; ++t) wq[t] = w14[t * 8 + q];
        float4 bq = ((const float4*)b1)[q];

        // q==0: wait for simg staging; q>0: wait for prev conv2 reads of sh
        __syncthreads();

        // ---- conv1: 6 h-pixels per active thread ----
        if (c1act) {
            float4 acc[6];
#pragma unroll
            for (int j = 0; j < 6; ++j) acc[j] = bq;
#pragma unroll
            for (int ky = 0; ky < 5; ++ky) {
                const float* rp = c1base + ky * 76;
                float4 f0 = *(const float4*)(rp);
                float4 f1 = *(const float4*)(rp + 4);
                float4 f2 = *(const float4*)(rp + 8);
                float4 f3 = *(const float4*)(rp + 12);
                float f[16] = {f0.x, f0.y, f0.z, f0.w, f1.x, f1.y, f1.z, f1.w,
                               f2.x, f2.y, f2.z, f2.w, f3.x, f3.y, f3.z, f3.w};
#pragma unroll
                for (int j = 0; j < 6; ++j)
#pragma unroll
                    for (int kx = 0; kx < 5; ++kx) {
                        float v = f[2 * j + kx];
                        float4 w = wq[ky * 5 + kx];
                        acc[j].x += v * w.x; acc[j].y += v * w.y;
                        acc[j].z += v * w.z; acc[j].w += v * w.w;
                    }
            }
#pragma unroll
            for (int j = 0; j < 6; ++j) {
                float4 r;
                bool ok = rowok && ((unsigned)(gx0 + j) < 256u);
                r.x = ok ? fmaxf(acc[j].x, 0.f) : 0.f;
                r.y = ok ? fmaxf(acc[j].y, 0.f) : 0.f;
                r.z = ok ? fmaxf(acc[j].z, 0.f) : 0.f;
                r.w = ok ? fmaxf(acc[j].w, 0.f) : 0.f;
                shw[j] = r;
            }
        }

        // w2 quad into the same registers (independent of LDS; before sync)
        const float4* w24 = (const float4*)w2;
#pragma unroll
        for (int t = 0; t < 25; ++t) wq[t] = w24[t * 8 + q];

        __syncthreads();

        // ---- conv2 partial: 4 outputs/thread, vertical register reuse ----
#pragma unroll
        for (int rr = 0; rr < 8; ++rr) {
#pragma unroll
            for (int kx = 0; kx < 5; ++kx) {
                float4 hv = hb[rr * 37 + kx];
#pragma unroll
                for (int j = 0; j < 4; ++j) {
                    int ky = rr - j;
                    if (ky < 0 || ky > 4) continue;
                    float4 w = wq[ky * 5 + kx];
                    float d = hv.x * w.x + hv.y * w.y + hv.z * w.z + hv.w * w.w;
                    if (j == 0) z0 += d;
                    else if (j == 1) z1 += d;
                    else if (j == 2) z2 += d;
                    else z3 += d;
                }
            }
        }
    }

    size_t ob = ((size_t)b << 16) + ((size_t)(Y0 + ry0) << 8) + (X0 + cx);
    cms[ob]       = 1.f / (1.f + expf(-z0));
    cms[ob + 256] = 1.f / (1.f + expf(-z1));
    cms[ob + 512] = 1.f / (1.f + expf(-z2));
    cms[ob + 768] = 1.f / (1.f + expf(-z3));
}

// 3x3 NMS + threshold; LDS staging, one global atomic per row-block.
__global__ __launch_bounds__(256) void peak_scan_kernel(
    const float* __restrict__ cms, unsigned long long* __restrict__ keys,
    int* __restrict__ counts) {
    int b = blockIdx.x >> 8;
    int y = blockIdx.x & 255;
    int x = threadIdx.x;
    const float* cb = cms + ((size_t)b << 16);
    __shared__ float rows[3][256];
    __shared__ int lcnt, lbase;
    if (x == 0) lcnt = 0;
#pragma unroll
    for (int j = 0; j < 3; ++j) {
        int yy = y - 1 + j;
        rows[j][x] = (yy >= 0 && yy < HC) ? cb[yy * WC + x] : -INFINITY;
    }
    __syncthreads();
    float c = rows[1][x];
    bool peak = (c > 0.2f);
    if (peak) {
#pragma unroll
        for (int j = 0; j < 3; ++j) {
            float r0 = rows[j][x];
            float rl = (x > 0)   ? rows[j][x - 1] : -INFINITY;
            float rr = (x < 255) ? rows[j][x + 1] : -INFINITY;
            if (fmaxf(r0, fmaxf(rl, rr)) > c) peak = false;
        }
    }
    int p = -1;
    if (peak) p = atomicAdd(&lcnt, 1);
    __syncthreads();
    if (x == 0) lbase = lcnt ? atomicAdd(&counts[b * CNT_STRIDE], lcnt) : 0;
    __syncthreads();
    if (peak) {
        int pos = lbase + p;
        if (pos < CAP) {
            int i = y * WC + x;
            unsigned long long key =
                ((unsigned long long)__float_as_uint(c) << 32) |
                (unsigned long long)(0xFFFFFFFFu - (unsigned)i);
            keys[(size_t)b * CAP + pos] = key;
        }
    }
}

// Stage A: per (batch, chunk-of-1024) exact top-32 with removal, in LDS.
__global__ __launch_bounds__(256) void topk_stage_a(
    const unsigned long long* __restrict__ keys, const int* __restrict__ counts,
    unsigned long long* __restrict__ cand) {
    int b = blockIdx.x >> 4;
    int chunk = blockIdx.x & 15;
    int tid = threadIdx.x;
    __shared__ unsigned long long lk[CHUNK];
    __shared__ unsigned long long rkey[256];
    __shared__ int rpos[256];
    int cnt = counts[b * CNT_STRIDE]; if (cnt > CAP) cnt = CAP;
    const unsigned long long* kb = keys + (size_t)b * CAP + chunk * CHUNK;
    int lim = cnt - chunk * CHUNK;
#pragma unroll
    for (int k = 0; k < 4; ++k) {
        int i = tid + k * 256;
        lk[i] = (i < lim) ? kb[i] : 0ULL;
    }
    __syncthreads();
    unsigned long long* out = cand + (size_t)(b * NCHUNK + chunk) * KMAX;
    for (int k = 0; k < KMAX; ++k) {
        unsigned long long best = 0ULL; int bp = -1;
#pragma unroll
        for (int j = 0; j < 4; ++j) {
            int i = tid + j * 256;
            unsigned long long kk = lk[i];
            if (kk > best) { best = kk; bp = i; }
        }
        rkey[tid] = best; rpos[tid] = bp;
        __syncthreads();
        for (int s = 128; s > 0; s >>= 1) {
            if (tid < s && rkey[tid + s] > rkey[tid]) {
                rkey[tid] = rkey[tid + s]; rpos[tid] = rpos[tid + s];
            }
            __syncthreads();
        }
        unsigned long long w = rkey[0];
        if (w == 0ULL) {
            if (tid >= k && tid < KMAX) out[tid] = 0ULL;
            break;
        }
        if (tid == 0) { out[k] = w; lk[rpos[0]] = 0ULL; }
        __syncthreads();
    }
}

// Stage B: per batch, exact top-32 over 512 candidates + integral refinement.
__global__ __launch_bounds__(256) void topk_stage_b(
    const float* __restrict__ cms, const unsigned long long* __restrict__ cand,
    float* __restrict__ out_off, float* __restrict__ out_vals,
    float* __restrict__ out_valid, float* __restrict__ ws_cx,
    float* __restrict__ ws_cy, float* __restrict__ ws_v) {
    int b = blockIdx.x;
    int tid = threadIdx.x;
    __shared__ unsigned long long lk[NCHUNK * KMAX];   // 512
    __shared__ unsigned long long rkey[256];
    __shared__ int rpos[256];
    __shared__ unsigned long long sel[KMAX];
    lk[tid]       = cand[(size_t)b * 512 + tid];
    lk[tid + 256] = cand[(size_t)b * 512 + 256 + tid];
    if (tid < KMAX) sel[tid] = 0ULL;
    __syncthreads();
    for (int k = 0; k < KMAX; ++k) {
        unsigned long long best = 0ULL; int bp = -1;
        {
            unsigned long long k0 = lk[tid], k1 = lk[tid + 256];
            if (k0 > best) { best = k0; bp = tid; }
            if (k1 > best) { best = k1; bp = tid + 256; }
        }
        rkey[tid] = best; rpos[tid] = bp;
        __syncthreads();
        for (int s = 128; s > 0; s >>= 1) {
            if (tid < s && rkey[tid + s] > rkey[tid]) {
                rkey[tid] = rkey[tid + s]; rpos[tid] = rpos[tid + s];
            }
            __syncthreads();
        }
        unsigned long long w = rkey[0];
        if (w == 0ULL) break;
        if (tid == 0) { sel[k] = w; lk[rpos[0]] = 0ULL; }
        __syncthreads();
    }
    __syncthreads();
    if (tid < KMAX) {
        int k = tid;
        unsigned long long key = sel[k];
        bool valid = key != 0ULL;
        float cx = 80.f, cy = 80.f, val = 0.f;
        if (valid) {
            val = __uint_as_float((unsigned)(key >> 32));
            int idx = (int)(0xFFFFFFFFu - (unsigned)(key & 0xFFFFFFFFULL));
            int py = idx >> 8, px = idx & 255;
            const float* cb = cms + ((size_t)b << 16);
            float gv = 1e-12f, sdx = 0.f, sdy = 0.f;
#pragma unroll
            for (int oy = -2; oy <= 2; ++oy)
#pragma unroll
                for (int ox = -2; ox <= 2; ++ox) {
                    int yy = py + oy, xx = px + ox;
                    if (yy < 0 || yy >= HC || xx < 0 || xx >= WC) continue;
                    float pv = cb[yy * WC + xx];
                    gv += pv; sdx += pv * (float)ox; sdy += pv * (float)oy;
                }
            float dx = sdx / gv, dy = sdy / gv;
            cx = ((float)px + dx) * 4.f;
            cy = ((float)py + dy) * 4.f;
        }
        int o = b * KMAX + k;
        out_off[o * 2 + 0] = cx - 80.f;
        out_off[o * 2 + 1] = cy - 80.f;
        out_vals[o] = val;
        out_valid[o] = valid ? 1.f : 0.f;
        ws_cx[o] = cx; ws_cy[o] = cy; ws_v[o] = valid ? 1.f : 0.f;
    }
}

__global__ __launch_bounds__(256) void crop_kernel(
    const float* __restrict__ full, const float* __restrict__ ws_cx,
    const float* __restrict__ ws_cy, const float* __restrict__ ws_v,
    float* __restrict__ out_crops) {
    int bidx = blockIdx.x;
    int cid = bidx / 100;
    int pp = (bidx - cid * 100) * 256 + threadIdx.x;
    int b = cid >> 5;
    float cx = ws_cx[cid], cy = ws_cy[cid], v = ws_v[cid];
    int row = pp / CROPSZ, col = pp - row * CROPSZ;
    float sy = cy - 79.5f + (float)row;
    float sx = cx - 79.5f + (float)col;
    float y0f = floorf(sy), x0f = floorf(sx);
    float wy = sy - y0f, wx = sx - x0f;
    int y0 = (int)y0f, x0 = (int)x0f;
    int yi0 = min(max(y0, 0), HF - 1);
    int yi1 = min(max(y0 + 1, 0), HF - 1);
    int xi0 = min(max(x0, 0), WF - 1);
    int xi1 = min(max(x0 + 1, 0), WF - 1);
    const float* base = full + ((size_t)b << 20);
    float t00 = base[yi0 * WF + xi0];
    float t01 = base[yi0 * WF + xi1];
    float t10 = base[yi1 * WF + xi0];
    float t11 = base[yi1 * WF + xi1];
    float top = t00 * (1.f - wx) + t01 * wx;
    float bot = t10 * (1.f - wx) + t11 * wx;
    float val = top * (1.f - wy) + bot * wy;
    float inr = (sy >= 0.f && sy <= (float)(HF - 1) &&
                 sx >= 0.f && sx <= (float)(WF - 1)) ? 1.f : 0.f;
    out_crops[(size_t)cid * (CROPSZ * CROPSZ) + pp] = val * inr * v;
}

extern "C" void kernel_launch(void* const* d_in, const int* in_sizes, int n_in,
                              void* d_out, int out_size, void* d_ws, size_t ws_size,
                              hipStream_t stream) {
    const float* full = (const float*)d_in[0];
    const float* w1   = (const float*)d_in[1];
    const float* b1   = (const float*)d_in[2];
    const float* w2   = (const float*)d_in[3];
    const float* b2   = (const float*)d_in[4];

    char* ws = (char*)d_ws;
    float* imgs = (float*)(ws + OFF_IMGS);
    float* cms  = (float*)(ws + OFF_CMS);
    unsigned long long* keys = (unsigned long long*)(ws + OFF_KEYS);
    int* counts = (int*)(ws + OFF_CNT);
    float* ws_cx = (float*)(ws + OFF_CX);
    float* ws_cy = (float*)(ws + OFF_CY);
    float* ws_v  = (float*)(ws + OFF_VLD);
    unsigned long long* cand = (unsigned long long*)(ws + OFF_CAND);

    float* out = (float*)d_out;
    float* out_crops = out + OUT_CROPS;
    float* out_off   = out + OUT_OFFS;
    float* out_vals  = out + OUT_VALS;
    float* out_valid = out + OUT_VALID;

    hipLaunchKernelGGL(resize_kernel, dim3(512, 16), dim3(256), 0, stream,
                       full, imgs, counts);

    hipLaunchKernelGGL(conv_fused2_kernel, dim3(64, 16), dim3(256), 0, stream,
                       imgs, w1, b1, w2, b2, cms);

    hipLaunchKernelGGL(peak_scan_kernel, dim3(4096), dim3(256), 0, stream,
                       cms, keys, counts);
    hipLaunchKernelGGL(topk_stage_a, dim3(256), dim3(256), 0, stream,
                       keys, counts, cand);
    hipLaunchKernelGGL(topk_stage_b, dim3(16), dim3(256), 0, stream,
                       cms, cand, out_off, out_vals, out_valid,
                       ws_cx, ws_cy, ws_v);
    hipLaunchKernelGGL(crop_kernel, dim3(51200), dim3(256), 0, stream,
                       full, ws_cx, ws_cy, ws_v, out_crops);
}

// Round 3
// 283.174 us; speedup vs baseline: 1.2274x; 1.1432x over previous
//
#include <hip/hip_runtime.h>
#include <math.h>

#define BATCH 16
#define HF 1024
#define WF 1024
#define HS 512
#define WS2 512
#define HC 256
#define WC 256
#define KMAX 32
#define CAP 16384
#define CROPSZ 160
#define CNT_STRIDE 16
#define NCHUNK 16
#define CHUNK 1024

// ---- workspace byte offsets ----
#define OFF_IMGS 0UL                                   // 16*512*512 f32 = 16 MB
#define OFF_CMS  16777216UL                            // 16*256*256 f32 = 4 MB
#define OFF_KEYS 20971520UL                            // 16*16384 u64  = 2 MB
#define OFF_CNT  23068672UL                            // 16*16 int
#define OFF_CX   23070720UL                            // 512 f32
#define OFF_CY   (OFF_CX + 2048UL)
#define OFF_VLD  (OFF_CY + 2048UL)
#define OFF_CAND (OFF_VLD + 2048UL)                    // 16*16*32 u64 = 64 KB

// ---- output element offsets ----
#define OUT_CROPS 0
#define OUT_OFFS  13107200
#define OUT_VALS  13108224
#define OUT_VALID 13108736

// jax.image.resize(bilinear, antialias) at 0.5: 4-tap {1,3,3,1}/8, edge-renorm.
// R3: 4 output rows per block (10 source rows staged once, 40 KB LDS) ->
// HBM reads drop from 2x to 1.25x of the source image (128 MB -> 80 MB).
__global__ __launch_bounds__(256) void resize_kernel(const float* __restrict__ full,
                                                     float* __restrict__ imgs,
                                                     int* __restrict__ counts) {
    if (blockIdx.x == 0 && blockIdx.y == 0 && threadIdx.x < BATCH * CNT_STRIDE)
        counts[threadIdx.x] = 0;
    __shared__ float simg[10][1024];
    int tid = threadIdx.x;
    int y0 = blockIdx.x << 2;    // output rows y0..y0+3
    int b = blockIdx.y;
    const float* base = full + ((size_t)b << 20);
    // stage source rows 2*y0-1 .. 2*y0+8 (clamped; weight-0 rows are benign)
#pragma unroll
    for (int s = 0; s < 10; ++s) {
        int r = 2 * y0 - 1 + s;
        r = r < 0 ? 0 : (r > HF - 1 ? HF - 1 : r);
        ((float4*)simg[s])[tid] = ((const float4*)(base + r * WF))[tid];
    }
    __syncthreads();
    const float w4[4] = {0.125f, 0.375f, 0.375f, 0.125f};
#pragma unroll
    for (int p = 0; p < 2; ++p) {
        int x = tid + 256 * p;
        float wx[4];
        int rx[4];
        float sx = 0.f;
#pragma unroll
        for (int ii = 0; ii < 4; ++ii) {
            int c = 2 * x - 1 + ii;
            float wc = (c >= 0 && c < WF) ? w4[ii] : 0.f;
            wx[ii] = wc; sx += wc;
            rx[ii] = c < 0 ? 0 : (c >= WF ? WF - 1 : c);
        }
#pragma unroll
        for (int r = 0; r < 4; ++r) {
            int yy = y0 + r;
            float sy = 0.f;
            float wy[4];
#pragma unroll
            for (int j = 0; j < 4; ++j) {
                int rr = 2 * yy - 1 + j;
                float w = (rr >= 0 && rr < HF) ? w4[j] : 0.f;
                wy[j] = w; sy += w;
            }
            float acc = 0.f;
#pragma unroll
            for (int j = 0; j < 4; ++j) {
                float rowacc = 0.f;
                const float* sr = simg[2 * r + j];
#pragma unroll
                for (int ii = 0; ii < 4; ++ii) rowacc += wx[ii] * sr[rx[ii]];
                acc += wy[j] * rowacc;
            }
            imgs[((size_t)b << 18) + (yy << 9) + x] = acc * (1.f / (sy * sx));
        }
    }
}

// Fused conv1(5x5 s2, 1->32, relu) + conv2(5x5 s1, 32->1, sigmoid).
// Block = 32x32 cms tile; stream 8 channel-quads through one LDS h buffer.
// R3: conv2 accumulates straight into four float4 partial sums (400 FMA/quad,
// 16 independent chains) instead of a serial dot-product temp (500 ops).
__global__ __launch_bounds__(256) void conv_fused2_kernel(
    const float* __restrict__ imgs, const float* __restrict__ w1,
    const float* __restrict__ b1, const float* __restrict__ w2,
    const float* __restrict__ b2, float* __restrict__ cms) {
    __shared__ float simg[75][76];     // imgs tile [2Y0-5 .. 2Y0+69]
    __shared__ float4 sh[36][37];      // h quad tile, rows Y0-2 .. Y0+33
    int tid = threadIdx.x;
    int b = blockIdx.y;
    int Y0 = (blockIdx.x >> 3) << 5;   // 8x8 tiles of 32x32
    int X0 = (blockIdx.x & 7) << 5;

    // ---- stage imgs tile (zero outside image == conv1 zero-pad) ----
    const float* ib = imgs + ((size_t)b << 18);
    int r0 = 2 * Y0 - 5, c0 = 2 * X0 - 5;
    for (int i = tid; i < 75 * 76; i += 256) {
        int r = i / 76, c = i - r * 76;
        int gy = r0 + r, gx = c0 + c;
        float v = 0.f;
        if ((unsigned)gy < 512u && (unsigned)gx < 512u)
            v = ib[(gy << 9) + gx];
        simg[r][c] = v;
    }

    // ---- conv1 work assignment (hoisted; quad-invariant) ----
    bool c1act = tid < 216;
    int ghy = tid / 6;                         // 0..35
    int ghx0 = (tid - ghy * 6) * 6;            // 0,6,..,30
    const float* c1base = &simg[2 * ghy][2 * ghx0];
    float4* shw = &sh[ghy][ghx0];
    bool rowok = (unsigned)(Y0 - 2 + ghy) < 256u;
    int gx0 = X0 - 2 + ghx0;

    // ---- conv2 work assignment (hoisted) ----
    int cx = tid & 31;                 // output column within tile
    int ry0 = (tid >> 5) << 2;         // output rows ry0..ry0+3
    const float4* hb = &sh[ry0][cx];
    float4 zv0 = make_float4(0.f, 0.f, 0.f, 0.f);
    float4 zv1 = zv0, zv2 = zv0, zv3 = zv0;

    for (int q = 0; q < 8; ++q) {
        // w1 quad: uniform loads -> SGPRs
        float4 wq[25];
        const float4* w14 = (const float4*)w1;
#pragma unroll
        for (int t = 0; t < 25; ++t) wq[t] = w14[t * 8 + q];
        float4 bq = ((const float4*)b1)[q];

        __syncthreads();

        // ---- conv1: 6 h-pixels per active thread ----
        if (c1act) {
            float4 acc[6];
#pragma unroll
            for (int j = 0; j < 6; ++j) acc[j] = bq;
#pragma unroll
            for (int ky = 0; ky < 5; ++ky) {
                const float* rp = c1base + ky * 76;
                float4 f0 = *(const float4*)(rp);
                float4 f1 = *(const float4*)(rp + 4);
                float4 f2 = *(const float4*)(rp + 8);
                float4 f3 = *(const float4*)(rp + 12);
                float f[16] = {f0.x, f0.y, f0.z, f0.w, f1.x, f1.y, f1.z, f1.w,
                               f2.x, f2.y, f2.z, f2.w, f3.x, f3.y, f3.z, f3.w};
#pragma unroll
                for (int j = 0; j < 6; ++j)
#pragma unroll
                    for (int kx = 0; kx < 5; ++kx) {
                        float v = f[2 * j + kx];
                        float4 w = wq[ky * 5 + kx];
                        acc[j].x += v * w.x; acc[j].y += v * w.y;
                        acc[j].z += v * w.z; acc[j].w += v * w.w;
                    }
            }
#pragma unroll
            for (int j = 0; j < 6; ++j) {
                float4 r;
                bool ok = rowok && ((unsigned)(gx0 + j) < 256u);
                r.x = ok ? fmaxf(acc[j].x, 0.f) : 0.f;
                r.y = ok ? fmaxf(acc[j].y, 0.f) : 0.f;
                r.z = ok ? fmaxf(acc[j].z, 0.f) : 0.f;
                r.w = ok ? fmaxf(acc[j].w, 0.f) : 0.f;
                shw[j] = r;
            }
        }

        // w2 quad (independent of LDS; before sync)
        const float4* w24 = (const float4*)w2;
#pragma unroll
        for (int t = 0; t < 25; ++t) wq[t] = w24[t * 8 + q];

        __syncthreads();

        // ---- conv2 partial: 4 outputs/thread, vertical register reuse ----
#pragma unroll
        for (int rr = 0; rr < 8; ++rr) {
#pragma unroll
            for (int kx = 0; kx < 5; ++kx) {
                float4 hv = hb[rr * 37 + kx];
#pragma unroll
                for (int j = 0; j < 4; ++j) {
                    int ky = rr - j;
                    if (ky < 0 || ky > 4) continue;
                    float4 w = wq[ky * 5 + kx];
                    if (j == 0) {
                        zv0.x += hv.x * w.x; zv0.y += hv.y * w.y;
                        zv0.z += hv.z * w.z; zv0.w += hv.w * w.w;
                    } else if (j == 1) {
                        zv1.x += hv.x * w.x; zv1.y += hv.y * w.y;
                        zv1.z += hv.z * w.z; zv1.w += hv.w * w.w;
                    } else if (j == 2) {
                        zv2.x += hv.x * w.x; zv2.y += hv.y * w.y;
                        zv2.z += hv.z * w.z; zv2.w += hv.w * w.w;
                    } else {
                        zv3.x += hv.x * w.x; zv3.y += hv.y * w.y;
                        zv3.z += hv.z * w.z; zv3.w += hv.w * w.w;
                    }
                }
            }
        }
    }

    float bb = b2[0];
    float z0 = bb + zv0.x + zv0.y + zv0.z + zv0.w;
    float z1 = bb + zv1.x + zv1.y + zv1.z + zv1.w;
    float z2 = bb + zv2.x + zv2.y + zv2.z + zv2.w;
    float z3 = bb + zv3.x + zv3.y + zv3.z + zv3.w;
    size_t ob = ((size_t)b << 16) + ((size_t)(Y0 + ry0) << 8) + (X0 + cx);
    cms[ob]       = 1.f / (1.f + expf(-z0));
    cms[ob + 256] = 1.f / (1.f + expf(-z1));
    cms[ob + 512] = 1.f / (1.f + expf(-z2));
    cms[ob + 768] = 1.f / (1.f + expf(-z3));
}

// 3x3 NMS + threshold; LDS staging, one global atomic per row-block.
__global__ __launch_bounds__(256) void peak_scan_kernel(
    const float* __restrict__ cms, unsigned long long* __restrict__ keys,
    int* __restrict__ counts) {
    int b = blockIdx.x >> 8;
    int y = blockIdx.x & 255;
    int x = threadIdx.x;
    const float* cb = cms + ((size_t)b << 16);
    __shared__ float rows[3][256];
    __shared__ int lcnt, lbase;
    if (x == 0) lcnt = 0;
#pragma unroll
    for (int j = 0; j < 3; ++j) {
        int yy = y - 1 + j;
        rows[j][x] = (yy >= 0 && yy < HC) ? cb[yy * WC + x] : -INFINITY;
    }
    __syncthreads();
    float c = rows[1][x];
    bool peak = (c > 0.2f);
    if (peak) {
#pragma unroll
        for (int j = 0; j < 3; ++j) {
            float r0 = rows[j][x];
            float rl = (x > 0)   ? rows[j][x - 1] : -INFINITY;
            float rr = (x < 255) ? rows[j][x + 1] : -INFINITY;
            if (fmaxf(r0, fmaxf(rl, rr)) > c) peak = false;
        }
    }
    int p = -1;
    if (peak) p = atomicAdd(&lcnt, 1);
    __syncthreads();
    if (x == 0) lbase = lcnt ? atomicAdd(&counts[b * CNT_STRIDE], lcnt) : 0;
    __syncthreads();
    if (peak) {
        int pos = lbase + p;
        if (pos < CAP) {
            int i = y * WC + x;
            unsigned long long key =
                ((unsigned long long)__float_as_uint(c) << 32) |
                (unsigned long long)(0xFFFFFFFFu - (unsigned)i);
            keys[(size_t)b * CAP + pos] = key;
        }
    }
}

// Stage A (R3): one 64-lane wave per (batch, chunk). 1024 keys live in 16
// u64 registers/lane. Each of the 32 extractions: 15 register max-compares +
// 6-step shfl_xor butterfly + compare-clear (keys unique by construction, so
// v[j]==best clears exactly one copy). Zero barriers, zero LDS.
__global__ __launch_bounds__(64) void topk_stage_a(
    const unsigned long long* __restrict__ keys, const int* __restrict__ counts,
    unsigned long long* __restrict__ cand) {
    int b = blockIdx.x >> 4;
    int chunk = blockIdx.x & 15;
    int lane = threadIdx.x;
    int cnt = counts[b * CNT_STRIDE]; if (cnt > CAP) cnt = CAP;
    const unsigned long long* kb = keys + (size_t)b * CAP + chunk * CHUNK;
    int lim = cnt - chunk * CHUNK;
    unsigned long long v[16];
#pragma unroll
    for (int j = 0; j < 16; ++j) {
        int i = lane + (j << 6);
        v[j] = (i < lim) ? kb[i] : 0ULL;
    }
    unsigned long long* out = cand + (size_t)(b * NCHUNK + chunk) * KMAX;
    int k = 0;
    for (; k < KMAX; ++k) {
        unsigned long long best = v[0];
#pragma unroll
        for (int j = 1; j < 16; ++j) best = v[j] > best ? v[j] : best;
#pragma unroll
        for (int s = 1; s < 64; s <<= 1) {
            unsigned long long o = __shfl_xor(best, s, 64);
            if (o > best) best = o;
        }
        if (best == 0ULL) break;
        if (lane == 0) out[k] = best;
#pragma unroll
        for (int j = 0; j < 16; ++j) if (v[j] == best) v[j] = 0ULL;
    }
    if (lane >= k && lane < KMAX) out[lane] = 0ULL;
}

// Stage B (R3): one wave per batch; 512 candidates in 8 u64 regs/lane.
// Extraction as stage A; lane k keeps the k-th winner in a register, then
// lanes 0..31 do the integral refinement + output writes.
__global__ __launch_bounds__(64) void topk_stage_b(
    const float* __restrict__ cms, const unsigned long long* __restrict__ cand,
    float* __restrict__ out_off, float* __restrict__ out_vals,
    float* __restrict__ out_valid, float* __restrict__ ws_cx,
    float* __restrict__ ws_cy, float* __restrict__ ws_v) {
    int b = blockIdx.x;
    int lane = threadIdx.x;
    unsigned long long v[8];
#pragma unroll
    for (int j = 0; j < 8; ++j)
        v[j] = cand[(size_t)b * 512 + lane + (j << 6)];
    unsigned long long mysel = 0ULL;
    for (int k = 0; k < KMAX; ++k) {
        unsigned long long best = v[0];
#pragma unroll
        for (int j = 1; j < 8; ++j) best = v[j] > best ? v[j] : best;
#pragma unroll
        for (int s = 1; s < 64; s <<= 1) {
            unsigned long long o = __shfl_xor(best, s, 64);
            if (o > best) best = o;
        }
        if (best == 0ULL) break;
        if (lane == k) mysel = best;
#pragma unroll
        for (int j = 0; j < 8; ++j) if (v[j] == best) v[j] = 0ULL;
    }
    if (lane < KMAX) {
        unsigned long long key = mysel;
        bool valid = key != 0ULL;
        float cx = 80.f, cy = 80.f, val = 0.f;
        if (valid) {
            val = __uint_as_float((unsigned)(key >> 32));
            int idx = (int)(0xFFFFFFFFu - (unsigned)(key & 0xFFFFFFFFULL));
            int py = idx >> 8, px = idx & 255;
            const float* cb = cms + ((size_t)b << 16);
            float gv = 1e-12f, sdx = 0.f, sdy = 0.f;
#pragma unroll
            for (int oy = -2; oy <= 2; ++oy)
#pragma unroll
                for (int ox = -2; ox <= 2; ++ox) {
                    int yy = py + oy, xx = px + ox;
                    if (yy < 0 || yy >= HC || xx < 0 || xx >= WC) continue;
                    float pv = cb[yy * WC + xx];
                    gv += pv; sdx += pv * (float)ox; sdy += pv * (float)oy;
                }
            float dx = sdx / gv, dy = sdy / gv;
            cx = ((float)px + dx) * 4.f;
            cy = ((float)py + dy) * 4.f;
        }
        int o = b * KMAX + lane;
        out_off[o * 2 + 0] = cx - 80.f;
        out_off[o * 2 + 1] = cy - 80.f;
        out_vals[o] = val;
        out_valid[o] = valid ? 1.f : 0.f;
        ws_cx[o] = cx; ws_cy[o] = cy; ws_v[o] = valid ? 1.f : 0.f;
    }
}

__global__ __launch_bounds__(256) void crop_kernel(
    const float* __restrict__ full, const float* __restrict__ ws_cx,
    const float* __restrict__ ws_cy, const float* __restrict__ ws_v,
    float* __restrict__ out_crops) {
    int bidx = blockIdx.x;
    int cid = bidx / 100;
    int pp = (bidx - cid * 100) * 256 + threadIdx.x;
    int b = cid >> 5;
    float cx = ws_cx[cid], cy = ws_cy[cid], v = ws_v[cid];
    int row = pp / CROPSZ, col = pp - row * CROPSZ;
    float sy = cy - 79.5f + (float)row;
    float sx = cx - 79.5f + (float)col;
    float y0f = floorf(sy), x0f = floorf(sx);
    float wy = sy - y0f, wx = sx - x0f;
    int y0 = (int)y0f, x0 = (int)x0f;
    int yi0 = min(max(y0, 0), HF - 1);
    int yi1 = min(max(y0 + 1, 0), HF - 1);
    int xi0 = min(max(x0, 0), WF - 1);
    int xi1 = min(max(x0 + 1, 0), WF - 1);
    const float* base = full + ((size_t)b << 20);
    float t00 = base[yi0 * WF + xi0];
    float t01 = base[yi0 * WF + xi1];
    float t10 = base[yi1 * WF + xi0];
    float t11 = base[yi1 * WF + xi1];
    float top = t00 * (1.f - wx) + t01 * wx;
    float bot = t10 * (1.f - wx) + t11 * wx;
    float val = top * (1.f - wy) + bot * wy;
    float inr = (sy >= 0.f && sy <= (float)(HF - 1) &&
                 sx >= 0.f && sx <= (float)(WF - 1)) ? 1.f : 0.f;
    out_crops[(size_t)cid * (CROPSZ * CROPSZ) + pp] = val * inr * v;
}

extern "C" void kernel_launch(void* const* d_in, const int* in_sizes, int n_in,
                              void* d_out, int out_size, void* d_ws, size_t ws_size,
                              hipStream_t stream) {
    const float* full = (const float*)d_in[0];
    const float* w1   = (const float*)d_in[1];
    const float* b1   = (const float*)d_in[2];
    const float* w2   = (const float*)d_in[3];
    const float* b2   = (const float*)d_in[4];

    char* ws = (char*)d_ws;
    float* imgs = (float*)(ws + OFF_IMGS);
    float* cms  = (float*)(ws + OFF_CMS);
    unsigned long long* keys = (unsigned long long*)(ws + OFF_KEYS);
    int* counts = (int*)(ws + OFF_CNT);
    float* ws_cx = (float*)(ws + OFF_CX);
    float* ws_cy = (float*)(ws + OFF_CY);
    float* ws_v  = (float*)(ws + OFF_VLD);
    unsigned long long* cand = (unsigned long long*)(ws + OFF_CAND);

    float* out = (float*)d_out;
    float* out_crops = out + OUT_CROPS;
    float* out_off   = out + OUT_OFFS;
    float* out_vals  = out + OUT_VALS;
    float* out_valid = out + OUT_VALID;

    hipLaunchKernelGGL(resize_kernel, dim3(128, 16), dim3(256), 0, stream,
                       full, imgs, counts);

    hipLaunchKernelGGL(conv_fused2_kernel, dim3(64, 16), dim3(256), 0, stream,
                       imgs, w1, b1, w2, b2, cms);

    hipLaunchKernelGGL(peak_scan_kernel, dim3(4096), dim3(256), 0, stream,
                       cms, keys, counts);
    hipLaunchKernelGGL(topk_stage_a, dim3(256), dim3(64), 0, stream,
                       keys, counts, cand);
    hipLaunchKernelGGL(topk_stage_b, dim3(16), dim3(64), 0, stream,
                       cms, cand, out_off, out_vals, out_valid,
                       ws_cx, ws_cy, ws_v);
    hipLaunchKernelGGL(crop_kernel, dim3(51200), dim3(256), 0, stream,
                       full, ws_cx, ws_cy, ws_v, out_crops);
}

// Round 4
// 262.742 us; speedup vs baseline: 1.3228x; 1.0778x over previous
//
#include <hip/hip_runtime.h>
#include <math.h>

#define BATCH 16
#define HF 1024
#define WF 1024
#define HS 512
#define WS2 512
#define HC 256
#define WC 256
#define KMAX 32
#define CAP 16384
#define CROPSZ 160
#define CNT_STRIDE 16
#define NCHUNK 16
#define CHUNK 1024

// Guard-padded resized image: 5-px zero border so conv1's 5x5 s2 window can
// read unconditionally (SAME zero-padding == guard zeros). Rows used: [-5,517]
// -> padded rows [0,522]; cols [-5,518] -> padded cols [0,523].
#define IMGP_W 524
#define IMGP_H 524
#define IMGP_STRIDE (IMGP_W * IMGP_H)   // floats per batch = 274576

// ---- workspace byte offsets ----
#define OFF_IMGS 0UL                                   // 16*524*524*4 = 17572864
#define OFF_CMS  17572864UL                            // 16*256*256 f32 = 4 MB
#define OFF_KEYS (OFF_CMS + 4194304UL)
#define OFF_CNT  (OFF_KEYS + 2097152UL)
#define OFF_CX   (OFF_CNT + 2048UL)
#define OFF_CY   (OFF_CX + 2048UL)
#define OFF_VLD  (OFF_CY + 2048UL)
#define OFF_CAND (OFF_VLD + 2048UL)                    // 16*16*32 u64 = 64 KB

// ---- output element offsets ----
#define OUT_CROPS 0
#define OUT_OFFS  13107200
#define OUT_VALS  13108224
#define OUT_VALID 13108736

// jax.image.resize(bilinear, antialias) at 0.5: 4-tap {1,3,3,1}/8, edge-renorm.
// R4: writes into the guard-padded imgs layout and zeroes the guards (must be
// re-zeroed every launch: workspace may be re-poisoned between iterations).
__global__ __launch_bounds__(256) void resize_kernel(const float* __restrict__ full,
                                                     float* __restrict__ imgs,
                                                     int* __restrict__ counts) {
    if (blockIdx.x == 0 && blockIdx.y == 0 && threadIdx.x < BATCH * CNT_STRIDE)
        counts[threadIdx.x] = 0;
    __shared__ float simg[10][1024];
    int tid = threadIdx.x;
    int y0 = blockIdx.x << 2;    // output rows y0..y0+3
    int b = blockIdx.y;
    const float* base = full + ((size_t)b << 20);
    float* ob = imgs + (size_t)b * IMGP_STRIDE;
    // ---- zero guards ----
    if (tid < 48) {              // left/right guards for this block's 4 rows
        int r = tid / 12, c = tid - (tid / 12) * 12;
        int col = c < 5 ? c : 512 + c;     // cols 0..4 and 517..523
        ob[(size_t)(5 + y0 + r) * IMGP_W + col] = 0.f;
    }
    if (blockIdx.x == 0)
        for (int i = tid; i < 5 * IMGP_W; i += 256) ob[i] = 0.f;         // top
    if (blockIdx.x == 127)
        for (int i = tid; i < 7 * IMGP_W; i += 256)
            ob[(size_t)517 * IMGP_W + i] = 0.f;                          // bottom
    // stage source rows 2*y0-1 .. 2*y0+8 (clamped; weight-0 rows are benign)
#pragma unroll
    for (int s = 0; s < 10; ++s) {
        int r = 2 * y0 - 1 + s;
        r = r < 0 ? 0 : (r > HF - 1 ? HF - 1 : r);
        ((float4*)simg[s])[tid] = ((const float4*)(base + r * WF))[tid];
    }
    __syncthreads();
    const float w4[4] = {0.125f, 0.375f, 0.375f, 0.125f};
#pragma unroll
    for (int p = 0; p < 2; ++p) {
        int x = tid + 256 * p;
        float wx[4];
        int rx[4];
        float sx = 0.f;
#pragma unroll
        for (int ii = 0; ii < 4; ++ii) {
            int c = 2 * x - 1 + ii;
            float wc = (c >= 0 && c < WF) ? w4[ii] : 0.f;
            wx[ii] = wc; sx += wc;
            rx[ii] = c < 0 ? 0 : (c >= WF ? WF - 1 : c);
        }
#pragma unroll
        for (int r = 0; r < 4; ++r) {
            int yy = y0 + r;
            float sy = 0.f;
            float wy[4];
#pragma unroll
            for (int j = 0; j < 4; ++j) {
                int rr = 2 * yy - 1 + j;
                float w = (rr >= 0 && rr < HF) ? w4[j] : 0.f;
                wy[j] = w; sy += w;
            }
            float acc = 0.f;
#pragma unroll
            for (int j = 0; j < 4; ++j) {
                float rowacc = 0.f;
                const float* sr = simg[2 * r + j];
#pragma unroll
                for (int ii = 0; ii < 4; ++ii) rowacc += wx[ii] * sr[rx[ii]];
                acc += wy[j] * rowacc;
            }
            ob[(size_t)(5 + yy) * IMGP_W + 5 + x] = acc * (1.f / (sy * sx));
        }
    }
}

// Fused conv1(5x5 s2, 1->32, relu) + conv2(5x5 s1, 32->1, sigmoid).
// Block = 32x32 cms tile; stream 8 channel-quads through one LDS h buffer.
// R4: conv1 reads the guard-padded imgs DIRECTLY from global (branch-free,
// 20 b128 loads/quad; tile re-read 8x but L2-resident: 2.9 MB/XCD < 4 MB).
// LDS = sh only (21.3 KB) -> 7 blocks/CU; grid 1024 = 4/CU in ONE round
// (R3's 44.5 KB allowed 3/CU -> 256-block tail round at 1/CU, occ 25%).
// Pointer-launder pins the global loads inside the quad loop (blocks LICM
// from hoisting 80 floats into registers).
__global__ __launch_bounds__(256, 4) void conv_fused2_kernel(
    const float* __restrict__ imgs, const float* __restrict__ w1,
    const float* __restrict__ b1, const float* __restrict__ w2,
    const float* __restrict__ b2, float* __restrict__ cms) {
    __shared__ float4 sh[36][37];      // h quad tile, rows Y0-2 .. Y0+33
    int tid = threadIdx.x;
    int b = blockIdx.y;
    int Y0 = (blockIdx.x >> 3) << 5;   // 8x8 tiles of 32x32
    int X0 = (blockIdx.x & 7) << 5;
    const float* ib = imgs + (size_t)b * IMGP_STRIDE;

    // ---- conv1 work assignment (hoisted; quad-invariant) ----
    bool c1act = tid < 216;
    int ghy = tid / 6;                         // 0..35
    int ghx0 = (tid - ghy * 6) * 6;            // 0,6,..,30
    // h-px (Y0-2+ghy, X0-2+ghx0+j) needs img rows 2(Y0-2+ghy)-1+ky =
    // 2Y0+2ghy-5+ky -> padded row 2Y0+2ghy+ky; cols padded 2X0+2ghx0+[0,15].
    const float* gbase = ib + (size_t)(2 * Y0 + 2 * ghy) * IMGP_W
                            + (2 * X0 + 2 * ghx0);
    float4* shw = &sh[ghy][ghx0];
    bool rowok = (unsigned)(Y0 - 2 + ghy) < 256u;
    int gx0 = X0 - 2 + ghx0;

    // ---- conv2 work assignment (hoisted) ----
    int cx = tid & 31;                 // output column within tile
    int ry0 = (tid >> 5) << 2;         // output rows ry0..ry0+3
    const float4* hb = &sh[ry0][cx];
    float4 zv0 = make_float4(0.f, 0.f, 0.f, 0.f);
    float4 zv1 = zv0, zv2 = zv0, zv3 = zv0;

    for (int q = 0; q < 8; ++q) {
        // w1 quad: uniform loads -> SGPRs
        float4 wq[25];
        const float4* w14 = (const float4*)w1;
#pragma unroll
        for (int t = 0; t < 25; ++t) wq[t] = w14[t * 8 + q];
        float4 bq = ((const float4*)b1)[q];

        // launder: opaque per-iteration offset so loads can't be hoisted
        int qoff = 0;
        asm volatile("" : "+v"(qoff));
        const float* gb = gbase + qoff;

        __syncthreads();   // prev conv2 reads of sh done before overwrite

        // ---- conv1: 6 h-pixels per active thread, global reads ----
        if (c1act) {
            float4 acc[6];
#pragma unroll
            for (int j = 0; j < 6; ++j) acc[j] = bq;
#pragma unroll
            for (int ky = 0; ky < 5; ++ky) {
                const float* rp = gb + ky * IMGP_W;
                float4 f0 = *(const float4*)(rp);
                float4 f1 = *(const float4*)(rp + 4);
                float4 f2 = *(const float4*)(rp + 8);
                float4 f3 = *(const float4*)(rp + 12);
                float f[16] = {f0.x, f0.y, f0.z, f0.w, f1.x, f1.y, f1.z, f1.w,
                               f2.x, f2.y, f2.z, f2.w, f3.x, f3.y, f3.z, f3.w};
#pragma unroll
                for (int j = 0; j < 6; ++j)
#pragma unroll
                    for (int kx = 0; kx < 5; ++kx) {
                        float v = f[2 * j + kx];
                        float4 w = wq[ky * 5 + kx];
                        acc[j].x += v * w.x; acc[j].y += v * w.y;
                        acc[j].z += v * w.z; acc[j].w += v * w.w;
                    }
            }
#pragma unroll
            for (int j = 0; j < 6; ++j) {
                float4 r;
                bool ok = rowok && ((unsigned)(gx0 + j) < 256u);
                r.x = ok ? fmaxf(acc[j].x, 0.f) : 0.f;
                r.y = ok ? fmaxf(acc[j].y, 0.f) : 0.f;
                r.z = ok ? fmaxf(acc[j].z, 0.f) : 0.f;
                r.w = ok ? fmaxf(acc[j].w, 0.f) : 0.f;
                shw[j] = r;
            }
        }

        // w2 quad (independent of LDS; before sync)
        const float4* w24 = (const float4*)w2;
#pragma unroll
        for (int t = 0; t < 25; ++t) wq[t] = w24[t * 8 + q];

        __syncthreads();

        // ---- conv2 partial: 4 outputs/thread, vertical register reuse ----
#pragma unroll
        for (int rr = 0; rr < 8; ++rr) {
#pragma unroll
            for (int kx = 0; kx < 5; ++kx) {
                float4 hv = hb[rr * 37 + kx];
#pragma unroll
                for (int j = 0; j < 4; ++j) {
                    int ky = rr - j;
                    if (ky < 0 || ky > 4) continue;
                    float4 w = wq[ky * 5 + kx];
                    if (j == 0) {
                        zv0.x += hv.x * w.x; zv0.y += hv.y * w.y;
                        zv0.z += hv.z * w.z; zv0.w += hv.w * w.w;
                    } else if (j == 1) {
                        zv1.x += hv.x * w.x; zv1.y += hv.y * w.y;
                        zv1.z += hv.z * w.z; zv1.w += hv.w * w.w;
                    } else if (j == 2) {
                        zv2.x += hv.x * w.x; zv2.y += hv.y * w.y;
                        zv2.z += hv.z * w.z; zv2.w += hv.w * w.w;
                    } else {
                        zv3.x += hv.x * w.x; zv3.y += hv.y * w.y;
                        zv3.z += hv.z * w.z; zv3.w += hv.w * w.w;
                    }
                }
            }
        }
    }

    float bb = b2[0];
    float z0 = bb + zv0.x + zv0.y + zv0.z + zv0.w;
    float z1 = bb + zv1.x + zv1.y + zv1.z + zv1.w;
    float z2 = bb + zv2.x + zv2.y + zv2.z + zv2.w;
    float z3 = bb + zv3.x + zv3.y + zv3.z + zv3.w;
    size_t ob = ((size_t)b << 16) + ((size_t)(Y0 + ry0) << 8) + (X0 + cx);
    cms[ob]       = 1.f / (1.f + expf(-z0));
    cms[ob + 256] = 1.f / (1.f + expf(-z1));
    cms[ob + 512] = 1.f / (1.f + expf(-z2));
    cms[ob + 768] = 1.f / (1.f + expf(-z3));
}

// 3x3 NMS + threshold; LDS staging, one global atomic per row-block.
__global__ __launch_bounds__(256) void peak_scan_kernel(
    const float* __restrict__ cms, unsigned long long* __restrict__ keys,
    int* __restrict__ counts) {
    int b = blockIdx.x >> 8;
    int y = blockIdx.x & 255;
    int x = threadIdx.x;
    const float* cb = cms + ((size_t)b << 16);
    __shared__ float rows[3][256];
    __shared__ int lcnt, lbase;
    if (x == 0) lcnt = 0;
#pragma unroll
    for (int j = 0; j < 3; ++j) {
        int yy = y - 1 + j;
        rows[j][x] = (yy >= 0 && yy < HC) ? cb[yy * WC + x] : -INFINITY;
    }
    __syncthreads();
    float c = rows[1][x];
    bool peak = (c > 0.2f);
    if (peak) {
#pragma unroll
        for (int j = 0; j < 3; ++j) {
            float r0 = rows[j][x];
            float rl = (x > 0)   ? rows[j][x - 1] : -INFINITY;
            float rr = (x < 255) ? rows[j][x + 1] : -INFINITY;
            if (fmaxf(r0, fmaxf(rl, rr)) > c) peak = false;
        }
    }
    int p = -1;
    if (peak) p = atomicAdd(&lcnt, 1);
    __syncthreads();
    if (x == 0) lbase = lcnt ? atomicAdd(&counts[b * CNT_STRIDE], lcnt) : 0;
    __syncthreads();
    if (peak) {
        int pos = lbase + p;
        if (pos < CAP) {
            int i = y * WC + x;
            unsigned long long key =
                ((unsigned long long)__float_as_uint(c) << 32) |
                (unsigned long long)(0xFFFFFFFFu - (unsigned)i);
            keys[(size_t)b * CAP + pos] = key;
        }
    }
}

// Stage A: one 64-lane wave per (batch, chunk). 1024 keys in 16 u64 regs/lane;
// 32 extractions of {15 reg max + 6-step shfl_xor butterfly + compare-clear}.
__global__ __launch_bounds__(64) void topk_stage_a(
    const unsigned long long* __restrict__ keys, const int* __restrict__ counts,
    unsigned long long* __restrict__ cand) {
    int b = blockIdx.x >> 4;
    int chunk = blockIdx.x & 15;
    int lane = threadIdx.x;
    int cnt = counts[b * CNT_STRIDE]; if (cnt > CAP) cnt = CAP;
    const unsigned long long* kb = keys + (size_t)b * CAP + chunk * CHUNK;
    int lim = cnt - chunk * CHUNK;
    unsigned long long v[16];
#pragma unroll
    for (int j = 0; j < 16; ++j) {
        int i = lane + (j << 6);
        v[j] = (i < lim) ? kb[i] : 0ULL;
    }
    unsigned long long* out = cand + (size_t)(b * NCHUNK + chunk) * KMAX;
    int k = 0;
    for (; k < KMAX; ++k) {
        unsigned long long best = v[0];
#pragma unroll
        for (int j = 1; j < 16; ++j) best = v[j] > best ? v[j] : best;
#pragma unroll
        for (int s = 1; s < 64; s <<= 1) {
            unsigned long long o = __shfl_xor(best, s, 64);
            if (o > best) best = o;
        }
        if (best == 0ULL) break;
        if (lane == 0) out[k] = best;
#pragma unroll
        for (int j = 0; j < 16; ++j) if (v[j] == best) v[j] = 0ULL;
    }
    if (lane >= k && lane < KMAX) out[lane] = 0ULL;
}

// Stage B: one wave per batch; 512 candidates in 8 u64 regs/lane.
__global__ __launch_bounds__(64) void topk_stage_b(
    const float* __restrict__ cms, const unsigned long long* __restrict__ cand,
    float* __restrict__ out_off, float* __restrict__ out_vals,
    float* __restrict__ out_valid, float* __restrict__ ws_cx,
    float* __restrict__ ws_cy, float* __restrict__ ws_v) {
    int b = blockIdx.x;
    int lane = threadIdx.x;
    unsigned long long v[8];
#pragma unroll
    for (int j = 0; j < 8; ++j)
        v[j] = cand[(size_t)b * 512 + lane + (j << 6)];
    unsigned long long mysel = 0ULL;
    for (int k = 0; k < KMAX; ++k) {
        unsigned long long best = v[0];
#pragma unroll
        for (int j = 1; j < 8; ++j) best = v[j] > best ? v[j] : best;
#pragma unroll
        for (int s = 1; s < 64; s <<= 1) {
            unsigned long long o = __shfl_xor(best, s, 64);
            if (o > best) best = o;
        }
        if (best == 0ULL) break;
        if (lane == k) mysel = best;
#pragma unroll
        for (int j = 0; j < 8; ++j) if (v[j] == best) v[j] = 0ULL;
    }
    if (lane < KMAX) {
        unsigned long long key = mysel;
        bool valid = key != 0ULL;
        float cx = 80.f, cy = 80.f, val = 0.f;
        if (valid) {
            val = __uint_as_float((unsigned)(key >> 32));
            int idx = (int)(0xFFFFFFFFu - (unsigned)(key & 0xFFFFFFFFULL));
            int py = idx >> 8, px = idx & 255;
            const float* cb = cms + ((size_t)b << 16);
            float gv = 1e-12f, sdx = 0.f, sdy = 0.f;
#pragma unroll
            for (int oy = -2; oy <= 2; ++oy)
#pragma unroll
                for (int ox = -2; ox <= 2; ++ox) {
                    int yy = py + oy, xx = px + ox;
                    if (yy < 0 || yy >= HC || xx < 0 || xx >= WC) continue;
                    float pv = cb[yy * WC + xx];
                    gv += pv; sdx += pv * (float)ox; sdy += pv * (float)oy;
                }
            float dx = sdx / gv, dy = sdy / gv;
            cx = ((float)px + dx) * 4.f;
            cy = ((float)py + dy) * 4.f;
        }
        int o = b * KMAX + lane;
        out_off[o * 2 + 0] = cx - 80.f;
        out_off[o * 2 + 1] = cy - 80.f;
        out_vals[o] = val;
        out_valid[o] = valid ? 1.f : 0.f;
        ws_cx[o] = cx; ws_cy[o] = cy; ws_v[o] = valid ? 1.f : 0.f;
    }
}

// R4: 4 output rows per thread. wy = frac(cy-79.5) is crop-constant and
// y0(r+1) = y0(r)+1, so 5 row-interpolations serve 4 output rows:
// 2.5 loads/px instead of 4. 25 blocks per crop; lanes = consecutive cols.
__global__ __launch_bounds__(256) void crop_kernel(
    const float* __restrict__ full, const float* __restrict__ ws_cx,
    const float* __restrict__ ws_cy, const float* __restrict__ ws_v,
    float* __restrict__ out_crops) {
    int bidx = blockIdx.x;
    int cid = bidx / 25;
    int p = (bidx - cid * 25) * 256 + threadIdx.x;   // 0..6399
    int b = cid >> 5;
    float cx = ws_cx[cid], cy = ws_cy[cid], v = ws_v[cid];
    int rg = p / CROPSZ;             // row group 0..39
    int col = p - rg * CROPSZ;
    int r0 = rg << 2;                // output rows r0..r0+3
    float sx = cx - 79.5f + (float)col;
    float x0f = floorf(sx);
    float wx = sx - x0f;
    int x0 = (int)x0f;
    int xi0 = min(max(x0, 0), WF - 1);
    int xi1 = min(max(x0 + 1, 0), WF - 1);
    float syb = cy - 79.5f + (float)r0;
    float y0f = floorf(syb);
    float wy = syb - y0f;
    int y0 = (int)y0f;
    const float* base = full + ((size_t)b << 20);
    float rv[5];
#pragma unroll
    for (int i = 0; i < 5; ++i) {
        int yy = min(max(y0 + i, 0), HF - 1);
        float a = base[yy * WF + xi0];
        float c = base[yy * WF + xi1];
        rv[i] = a * (1.f - wx) + c * wx;
    }
    bool xin = (sx >= 0.f && sx <= (float)(WF - 1));
    size_t ob = (size_t)cid * (CROPSZ * CROPSZ) + r0 * CROPSZ + col;
#pragma unroll
    for (int i = 0; i < 4; ++i) {
        float sy = syb + (float)i;
        float val = rv[i] * (1.f - wy) + rv[i + 1] * wy;
        float inr = (xin && sy >= 0.f && sy <= (float)(HF - 1)) ? 1.f : 0.f;
        out_crops[ob + i * CROPSZ] = val * inr * v;
    }
}

extern "C" void kernel_launch(void* const* d_in, const int* in_sizes, int n_in,
                              void* d_out, int out_size, void* d_ws, size_t ws_size,
                              hipStream_t stream) {
    const float* full = (const float*)d_in[0];
    const float* w1   = (const float*)d_in[1];
    const float* b1   = (const float*)d_in[2];
    const float* w2   = (const float*)d_in[3];
    const float* b2   = (const float*)d_in[4];

    char* ws = (char*)d_ws;
    float* imgs = (float*)(ws + OFF_IMGS);
    float* cms  = (float*)(ws + OFF_CMS);
    unsigned long long* keys = (unsigned long long*)(ws + OFF_KEYS);
    int* counts = (int*)(ws + OFF_CNT);
    float* ws_cx = (float*)(ws + OFF_CX);
    float* ws_cy = (float*)(ws + OFF_CY);
    float* ws_v  = (float*)(ws + OFF_VLD);
    unsigned long long* cand = (unsigned long long*)(ws + OFF_CAND);

    float* out = (float*)d_out;
    float* out_crops = out + OUT_CROPS;
    float* out_off   = out + OUT_OFFS;
    float* out_vals  = out + OUT_VALS;
    float* out_valid = out + OUT_VALID;

    hipLaunchKernelGGL(resize_kernel, dim3(128, 16), dim3(256), 0, stream,
                       full, imgs, counts);

    hipLaunchKernelGGL(conv_fused2_kernel, dim3(64, 16), dim3(256), 0, stream,
                       imgs, w1, b1, w2, b2, cms);

    hipLaunchKernelGGL(peak_scan_kernel, dim3(4096), dim3(256), 0, stream,
                       cms, keys, counts);
    hipLaunchKernelGGL(topk_stage_a, dim3(256), dim3(64), 0, stream,
                       keys, counts, cand);
    hipLaunchKernelGGL(topk_stage_b, dim3(16), dim3(64), 0, stream,
                       cms, cand, out_off, out_vals, out_valid,
                       ws_cx, ws_cy, ws_v);
    hipLaunchKernelGGL(crop_kernel, dim3(12800), dim3(256), 0, stream,
                       full, ws_cx, ws_cy, ws_v, out_crops);
}

// Round 5
// 251.512 us; speedup vs baseline: 1.3819x; 1.0447x over previous
//
#include <hip/hip_runtime.h>
#include <math.h>

#define BATCH 16
#define HF 1024
#define WF 1024
#define HS 512
#define WS2 512
#define HC 256
#define WC 256
#define KMAX 32
#define CAP 16384
#define CROPSZ 160
#define CNT_STRIDE 16
#define NCHUNK 16
#define CHUNK 1024

// Guard-padded resized image: 5-px zero border so conv1's 5x5 s2 window can
// read unconditionally (SAME zero-padding == guard zeros).
#define IMGP_W 524
#define IMGP_H 524
#define IMGP_STRIDE (IMGP_W * IMGP_H)   // floats per batch = 274576

// cms is now TWO pre-sigmoid partial planes (quad-split conv): plane A =
// bias + quads 0..3, plane B = quads 4..7. z = A + B; sigmoid applied by
// consumers (monotonic -> peak logic unchanged on z).
#define CMS_PLANE 1048576UL             // 16 * 65536 floats
#define THRESH_Z -1.38629436112f        // logit(0.2) = ln(0.25)

// ---- workspace byte offsets ----
#define OFF_IMGS 0UL                                   // 16*524*524*4 = 17572864
#define OFF_CMS  17572864UL                            // 2 planes * 4 MB
#define OFF_KEYS (OFF_CMS + 8388608UL)
#define OFF_CNT  (OFF_KEYS + 2097152UL)
#define OFF_CX   (OFF_CNT + 2048UL)
#define OFF_CY   (OFF_CX + 2048UL)
#define OFF_VLD  (OFF_CY + 2048UL)
#define OFF_CAND (OFF_VLD + 2048UL)                    // 16*16*32 u64 = 64 KB

// ---- output element offsets ----
#define OUT_CROPS 0
#define OUT_OFFS  13107200
#define OUT_VALS  13108224
#define OUT_VALID 13108736

// jax.image.resize(bilinear, antialias) at 0.5: 4-tap {1,3,3,1}/8, edge-renorm.
// Writes guard-padded layout; zeroes guards every launch (ws re-poisoned).
__global__ __launch_bounds__(256) void resize_kernel(const float* __restrict__ full,
                                                     float* __restrict__ imgs,
                                                     int* __restrict__ counts) {
    if (blockIdx.x == 0 && blockIdx.y == 0 && threadIdx.x < BATCH * CNT_STRIDE)
        counts[threadIdx.x] = 0;
    __shared__ float simg[10][1024];
    int tid = threadIdx.x;
    int y0 = blockIdx.x << 2;    // output rows y0..y0+3
    int b = blockIdx.y;
    const float* base = full + ((size_t)b << 20);
    float* ob = imgs + (size_t)b * IMGP_STRIDE;
    // ---- zero guards ----
    if (tid < 48) {              // left/right guards for this block's 4 rows
        int r = tid / 12, c = tid - (tid / 12) * 12;
        int col = c < 5 ? c : 512 + c;     // cols 0..4 and 517..523
        ob[(size_t)(5 + y0 + r) * IMGP_W + col] = 0.f;
    }
    if (blockIdx.x == 0)
        for (int i = tid; i < 5 * IMGP_W; i += 256) ob[i] = 0.f;         // top
    if (blockIdx.x == 127)
        for (int i = tid; i < 7 * IMGP_W; i += 256)
            ob[(size_t)517 * IMGP_W + i] = 0.f;                          // bottom
    // stage source rows 2*y0-1 .. 2*y0+8 (clamped; weight-0 rows are benign)
#pragma unroll
    for (int s = 0; s < 10; ++s) {
        int r = 2 * y0 - 1 + s;
        r = r < 0 ? 0 : (r > HF - 1 ? HF - 1 : r);
        ((float4*)simg[s])[tid] = ((const float4*)(base + r * WF))[tid];
    }
    __syncthreads();
    const float w4[4] = {0.125f, 0.375f, 0.375f, 0.125f};
#pragma unroll
    for (int p = 0; p < 2; ++p) {
        int x = tid + 256 * p;
        float wx[4];
        int rx[4];
        float sx = 0.f;
#pragma unroll
        for (int ii = 0; ii < 4; ++ii) {
            int c = 2 * x - 1 + ii;
            float wc = (c >= 0 && c < WF) ? w4[ii] : 0.f;
            wx[ii] = wc; sx += wc;
            rx[ii] = c < 0 ? 0 : (c >= WF ? WF - 1 : c);
        }
#pragma unroll
        for (int r = 0; r < 4; ++r) {
            int yy = y0 + r;
            float sy = 0.f;
            float wy[4];
#pragma unroll
            for (int j = 0; j < 4; ++j) {
                int rr = 2 * yy - 1 + j;
                float w = (rr >= 0 && rr < HF) ? w4[j] : 0.f;
                wy[j] = w; sy += w;
            }
            float acc = 0.f;
#pragma unroll
            for (int j = 0; j < 4; ++j) {
                float rowacc = 0.f;
                const float* sr = simg[2 * r + j];
#pragma unroll
                for (int ii = 0; ii < 4; ++ii) rowacc += wx[ii] * sr[rx[ii]];
                acc += wy[j] * rowacc;
            }
            ob[(size_t)(5 + yy) * IMGP_W + 5 + x] = acc * (1.f / (sy * sx));
        }
    }
}

// Fused conv1(5x5 s2, 1->32, relu) + conv2(5x5 s1, 32->1) — R5 quad-split.
// Block = (32x32 cms tile, half): half 0 computes quads 0-3 (+bias) -> plane A,
// half 1 computes quads 4-7 -> plane B. No sigmoid (consumers apply it).
// Doubles the grid to 2048 blocks (R4's 1024 = only 4/CU was the occupancy
// cap; LDS 21.5 KB allows 7/CU) with zero extra per-px FMA / LDS traffic.
__global__ __launch_bounds__(256, 4) void conv_fused2_kernel(
    const float* __restrict__ imgs, const float* __restrict__ w1,
    const float* __restrict__ b1, const float* __restrict__ w2,
    const float* __restrict__ b2, float* __restrict__ cms) {
    __shared__ float4 sh[36][37];      // h quad tile, rows Y0-2 .. Y0+33
    int tid = threadIdx.x;
    int b = blockIdx.y >> 1;
    int half = blockIdx.y & 1;
    int q0 = half << 2;
    int Y0 = (blockIdx.x >> 3) << 5;   // 8x8 tiles of 32x32
    int X0 = (blockIdx.x & 7) << 5;
    const float* ib = imgs + (size_t)b * IMGP_STRIDE;

    // ---- conv1 work assignment (hoisted; quad-invariant) ----
    bool c1act = tid < 216;
    int ghy = tid / 6;                         // 0..35
    int ghx0 = (tid - ghy * 6) * 6;            // 0,6,..,30
    const float* gbase = ib + (size_t)(2 * Y0 + 2 * ghy) * IMGP_W
                            + (2 * X0 + 2 * ghx0);
    float4* shw = &sh[ghy][ghx0];
    bool rowok = (unsigned)(Y0 - 2 + ghy) < 256u;
    int gx0 = X0 - 2 + ghx0;

    // ---- conv2 work assignment (hoisted) ----
    int cx = tid & 31;                 // output column within tile
    int ry0 = (tid >> 5) << 2;         // output rows ry0..ry0+3
    const float4* hb = &sh[ry0][cx];
    float4 zv0 = make_float4(0.f, 0.f, 0.f, 0.f);
    float4 zv1 = zv0, zv2 = zv0, zv3 = zv0;

    for (int qi = 0; qi < 4; ++qi) {
        int q = q0 + qi;
        // w1 quad: uniform loads -> SGPRs
        float4 wq[25];
        const float4* w14 = (const float4*)w1;
#pragma unroll
        for (int t = 0; t < 25; ++t) wq[t] = w14[t * 8 + q];
        float4 bq = ((const float4*)b1)[q];

        // launder: opaque per-iteration offset so loads can't be hoisted
        int qoff = 0;
        asm volatile("" : "+v"(qoff));
        const float* gb = gbase + qoff;

        __syncthreads();   // prev conv2 reads of sh done before overwrite

        // ---- conv1: 6 h-pixels per active thread, global reads ----
        if (c1act) {
            float4 acc[6];
#pragma unroll
            for (int j = 0; j < 6; ++j) acc[j] = bq;
#pragma unroll
            for (int ky = 0; ky < 5; ++ky) {
                const float* rp = gb + ky * IMGP_W;
                float4 f0 = *(const float4*)(rp);
                float4 f1 = *(const float4*)(rp + 4);
                float4 f2 = *(const float4*)(rp + 8);
                float4 f3 = *(const float4*)(rp + 12);
                float f[16] = {f0.x, f0.y, f0.z, f0.w, f1.x, f1.y, f1.z, f1.w,
                               f2.x, f2.y, f2.z, f2.w, f3.x, f3.y, f3.z, f3.w};
#pragma unroll
                for (int j = 0; j < 6; ++j)
#pragma unroll
                    for (int kx = 0; kx < 5; ++kx) {
                        float v = f[2 * j + kx];
                        float4 w = wq[ky * 5 + kx];
                        acc[j].x += v * w.x; acc[j].y += v * w.y;
                        acc[j].z += v * w.z; acc[j].w += v * w.w;
                    }
            }
#pragma unroll
            for (int j = 0; j < 6; ++j) {
                float4 r;
                bool ok = rowok && ((unsigned)(gx0 + j) < 256u);
                r.x = ok ? fmaxf(acc[j].x, 0.f) : 0.f;
                r.y = ok ? fmaxf(acc[j].y, 0.f) : 0.f;
                r.z = ok ? fmaxf(acc[j].z, 0.f) : 0.f;
                r.w = ok ? fmaxf(acc[j].w, 0.f) : 0.f;
                shw[j] = r;
            }
        }

        // w2 quad (independent of LDS; before sync)
        const float4* w24 = (const float4*)w2;
#pragma unroll
        for (int t = 0; t < 25; ++t) wq[t] = w24[t * 8 + q];

        __syncthreads();

        // ---- conv2 partial: 4 outputs/thread, vertical register reuse ----
#pragma unroll
        for (int rr = 0; rr < 8; ++rr) {
#pragma unroll
            for (int kx = 0; kx < 5; ++kx) {
                float4 hv = hb[rr * 37 + kx];
#pragma unroll
                for (int j = 0; j < 4; ++j) {
                    int ky = rr - j;
                    if (ky < 0 || ky > 4) continue;
                    float4 w = wq[ky * 5 + kx];
                    if (j == 0) {
                        zv0.x += hv.x * w.x; zv0.y += hv.y * w.y;
                        zv0.z += hv.z * w.z; zv0.w += hv.w * w.w;
                    } else if (j == 1) {
                        zv1.x += hv.x * w.x; zv1.y += hv.y * w.y;
                        zv1.z += hv.z * w.z; zv1.w += hv.w * w.w;
                    } else if (j == 2) {
                        zv2.x += hv.x * w.x; zv2.y += hv.y * w.y;
                        zv2.z += hv.z * w.z; zv2.w += hv.w * w.w;
                    } else {
                        zv3.x += hv.x * w.x; zv3.y += hv.y * w.y;
                        zv3.z += hv.z * w.z; zv3.w += hv.w * w.w;
                    }
                }
            }
        }
    }

    float bb = half ? 0.f : b2[0];
    float z0 = bb + zv0.x + zv0.y + zv0.z + zv0.w;
    float z1 = bb + zv1.x + zv1.y + zv1.z + zv1.w;
    float z2 = bb + zv2.x + zv2.y + zv2.z + zv2.w;
    float z3 = bb + zv3.x + zv3.y + zv3.z + zv3.w;
    size_t ob = (size_t)half * CMS_PLANE + ((size_t)b << 16)
              + ((size_t)(Y0 + ry0) << 8) + (X0 + cx);
    cms[ob]       = z0;
    cms[ob + 256] = z1;
    cms[ob + 512] = z2;
    cms[ob + 768] = z3;
}

// 3x3 NMS + threshold on z = A + B (monotonic == sigmoid semantics).
// R5: 4 output rows per block (1024 blocks, 1.5x row reads, 1 global atomic).
// Key: sign-flip monotone u32 of z | (0xFFFFFFFF - idx) tie-break.
__global__ __launch_bounds__(256) void peak_scan_kernel(
    const float* __restrict__ cms, unsigned long long* __restrict__ keys,
    int* __restrict__ counts) {
    int bidx = blockIdx.x;
    int b = bidx >> 6;
    int y0 = (bidx & 63) << 2;       // output rows y0..y0+3
    int x = threadIdx.x;
    const float* pa = cms + ((size_t)b << 16);
    const float* pb = cms + CMS_PLANE + ((size_t)b << 16);
    __shared__ float rows[6][256];
    __shared__ int lcnt, lbase;
    if (x == 0) lcnt = 0;
#pragma unroll
    for (int j = 0; j < 6; ++j) {
        int yy = y0 - 1 + j;
        rows[j][x] = (yy >= 0 && yy < HC)
                         ? pa[yy * WC + x] + pb[yy * WC + x] : -INFINITY;
    }
    __syncthreads();
    int pidx[4];
    unsigned long long pkey[4];
#pragma unroll
    for (int r = 0; r < 4; ++r) {
        float c = rows[r + 1][x];
        bool peak = (c > THRESH_Z);
        if (peak) {
#pragma unroll
            for (int j = 0; j < 3; ++j) {
                const float* rw = rows[r + j];
                float r0 = rw[x];
                float rl = (x > 0)   ? rw[x - 1] : -INFINITY;
                float rr = (x < 255) ? rw[x + 1] : -INFINITY;
                if (fmaxf(r0, fmaxf(rl, rr)) > c) peak = false;
            }
        }
        pidx[r] = -1;
        if (peak) {
            pidx[r] = atomicAdd(&lcnt, 1);
            unsigned u = __float_as_uint(c);
            u = (u & 0x80000000u) ? ~u : (u | 0x80000000u);
            int i = (y0 + r) * WC + x;
            pkey[r] = ((unsigned long long)u << 32) |
                      (unsigned long long)(0xFFFFFFFFu - (unsigned)i);
        }
    }
    __syncthreads();
    if (x == 0) lbase = lcnt ? atomicAdd(&counts[b * CNT_STRIDE], lcnt) : 0;
    __syncthreads();
#pragma unroll
    for (int r = 0; r < 4; ++r)
        if (pidx[r] >= 0) {
            int pos = lbase + pidx[r];
            if (pos < CAP) keys[(size_t)b * CAP + pos] = pkey[r];
        }
}

// Stage A: one 64-lane wave per (batch, chunk). 1024 keys in 16 u64 regs/lane;
// 32 extractions of {15 reg max + 6-step shfl_xor butterfly + compare-clear}.
__global__ __launch_bounds__(64) void topk_stage_a(
    const unsigned long long* __restrict__ keys, const int* __restrict__ counts,
    unsigned long long* __restrict__ cand) {
    int b = blockIdx.x >> 4;
    int chunk = blockIdx.x & 15;
    int lane = threadIdx.x;
    int cnt = counts[b * CNT_STRIDE]; if (cnt > CAP) cnt = CAP;
    const unsigned long long* kb = keys + (size_t)b * CAP + chunk * CHUNK;
    int lim = cnt - chunk * CHUNK;
    unsigned long long v[16];
#pragma unroll
    for (int j = 0; j < 16; ++j) {
        int i = lane + (j << 6);
        v[j] = (i < lim) ? kb[i] : 0ULL;
    }
    unsigned long long* out = cand + (size_t)(b * NCHUNK + chunk) * KMAX;
    int k = 0;
    for (; k < KMAX; ++k) {
        unsigned long long best = v[0];
#pragma unroll
        for (int j = 1; j < 16; ++j) best = v[j] > best ? v[j] : best;
#pragma unroll
        for (int s = 1; s < 64; s <<= 1) {
            unsigned long long o = __shfl_xor(best, s, 64);
            if (o > best) best = o;
        }
        if (best == 0ULL) break;
        if (lane == 0) out[k] = best;
#pragma unroll
        for (int j = 0; j < 16; ++j) if (v[j] == best) v[j] = 0ULL;
    }
    if (lane >= k && lane < KMAX) out[lane] = 0ULL;
}

// Stage B: one wave per batch; recovers z from the monotone key encoding,
// applies sigmoid for vals and the 5x5 integral-refinement patch (z = A+B).
__global__ __launch_bounds__(64) void topk_stage_b(
    const float* __restrict__ cms, const unsigned long long* __restrict__ cand,
    float* __restrict__ out_off, float* __restrict__ out_vals,
    float* __restrict__ out_valid, float* __restrict__ ws_cx,
    float* __restrict__ ws_cy, float* __restrict__ ws_v) {
    int b = blockIdx.x;
    int lane = threadIdx.x;
    unsigned long long v[8];
#pragma unroll
    for (int j = 0; j < 8; ++j)
        v[j] = cand[(size_t)b * 512 + lane + (j << 6)];
    unsigned long long mysel = 0ULL;
    for (int k = 0; k < KMAX; ++k) {
        unsigned long long best = v[0];
#pragma unroll
        for (int j = 1; j < 8; ++j) best = v[j] > best ? v[j] : best;
#pragma unroll
        for (int s = 1; s < 64; s <<= 1) {
            unsigned long long o = __shfl_xor(best, s, 64);
            if (o > best) best = o;
        }
        if (best == 0ULL) break;
        if (lane == k) mysel = best;
#pragma unroll
        for (int j = 0; j < 8; ++j) if (v[j] == best) v[j] = 0ULL;
    }
    if (lane < KMAX) {
        unsigned long long key = mysel;
        bool valid = key != 0ULL;
        float cx = 80.f, cy = 80.f, val = 0.f;
        if (valid) {
            unsigned f = (unsigned)(key >> 32);
            unsigned u = (f & 0x80000000u) ? (f & 0x7FFFFFFFu) : ~f;
            float z = __uint_as_float(u);
            val = 1.f / (1.f + expf(-z));
            int idx = (int)(0xFFFFFFFFu - (unsigned)(key & 0xFFFFFFFFULL));
            int py = idx >> 8, px = idx & 255;
            const float* pa = cms + ((size_t)b << 16);
            const float* pb = cms + CMS_PLANE + ((size_t)b << 16);
            float gv = 1e-12f, sdx = 0.f, sdy = 0.f;
#pragma unroll
            for (int oy = -2; oy <= 2; ++oy)
#pragma unroll
                for (int ox = -2; ox <= 2; ++ox) {
                    int yy = py + oy, xx = px + ox;
                    if (yy < 0 || yy >= HC || xx < 0 || xx >= WC) continue;
                    float zz = pa[yy * WC + xx] + pb[yy * WC + xx];
                    float pv = 1.f / (1.f + expf(-zz));
                    gv += pv; sdx += pv * (float)ox; sdy += pv * (float)oy;
                }
            float dx = sdx / gv, dy = sdy / gv;
            cx = ((float)px + dx) * 4.f;
            cy = ((float)py + dy) * 4.f;
        }
        int o = b * KMAX + lane;
        out_off[o * 2 + 0] = cx - 80.f;
        out_off[o * 2 + 1] = cy - 80.f;
        out_vals[o] = val;
        out_valid[o] = valid ? 1.f : 0.f;
        ws_cx[o] = cx; ws_cy[o] = cy; ws_v[o] = valid ? 1.f : 0.f;
    }
}

// 4 output rows per thread; wy crop-constant -> 5 row-interps serve 4 rows.
__global__ __launch_bounds__(256) void crop_kernel(
    const float* __restrict__ full, const float* __restrict__ ws_cx,
    const float* __restrict__ ws_cy, const float* __restrict__ ws_v,
    float* __restrict__ out_crops) {
    int bidx = blockIdx.x;
    int cid = bidx / 25;
    int p = (bidx - cid * 25) * 256 + threadIdx.x;   // 0..6399
    int b = cid >> 5;
    float cx = ws_cx[cid], cy = ws_cy[cid], v = ws_v[cid];
    int rg = p / CROPSZ;             // row group 0..39
    int col = p - rg * CROPSZ;
    int r0 = rg << 2;                // output rows r0..r0+3
    float sx = cx - 79.5f + (float)col;
    float x0f = floorf(sx);
    float wx = sx - x0f;
    int x0 = (int)x0f;
    int xi0 = min(max(x0, 0), WF - 1);
    int xi1 = min(max(x0 + 1, 0), WF - 1);
    float syb = cy - 79.5f + (float)r0;
    float y0f = floorf(syb);
    float wy = syb - y0f;
    int y0 = (int)y0f;
    const float* base = full + ((size_t)b << 20);
    float rv[5];
#pragma unroll
    for (int i = 0; i < 5; ++i) {
        int yy = min(max(y0 + i, 0), HF - 1);
        float a = base[yy * WF + xi0];
        float c = base[yy * WF + xi1];
        rv[i] = a * (1.f - wx) + c * wx;
    }
    bool xin = (sx >= 0.f && sx <= (float)(WF - 1));
    size_t ob = (size_t)cid * (CROPSZ * CROPSZ) + r0 * CROPSZ + col;
#pragma unroll
    for (int i = 0; i < 4; ++i) {
        float sy = syb + (float)i;
        float val = rv[i] * (1.f - wy) + rv[i + 1] * wy;
        float inr = (xin && sy >= 0.f && sy <= (float)(HF - 1)) ? 1.f : 0.f;
        out_crops[ob + i * CROPSZ] = val * inr * v;
    }
}

extern "C" void kernel_launch(void* const* d_in, const int* in_sizes, int n_in,
                              void* d_out, int out_size, void* d_ws, size_t ws_size,
                              hipStream_t stream) {
    const float* full = (const float*)d_in[0];
    const float* w1   = (const float*)d_in[1];
    const float* b1   = (const float*)d_in[2];
    const float* w2   = (const float*)d_in[3];
    const float* b2   = (const float*)d_in[4];

    char* ws = (char*)d_ws;
    float* imgs = (float*)(ws + OFF_IMGS);
    float* cms  = (float*)(ws + OFF_CMS);
    unsigned long long* keys = (unsigned long long*)(ws + OFF_KEYS);
    int* counts = (int*)(ws + OFF_CNT);
    float* ws_cx = (float*)(ws + OFF_CX);
    float* ws_cy = (float*)(ws + OFF_CY);
    float* ws_v  = (float*)(ws + OFF_VLD);
    unsigned long long* cand = (unsigned long long*)(ws + OFF_CAND);

    float* out = (float*)d_out;
    float* out_crops = out + OUT_CROPS;
    float* out_off   = out + OUT_OFFS;
    float* out_vals  = out + OUT_VALS;
    float* out_valid = out + OUT_VALID;

    hipLaunchKernelGGL(resize_kernel, dim3(128, 16), dim3(256), 0, stream,
                       full, imgs, counts);

    hipLaunchKernelGGL(conv_fused2_kernel, dim3(64, 32), dim3(256), 0, stream,
                       imgs, w1, b1, w2, b2, cms);

    hipLaunchKernelGGL(peak_scan_kernel, dim3(1024), dim3(256), 0, stream,
                       cms, keys, counts);
    hipLaunchKernelGGL(topk_stage_a, dim3(256), dim3(64), 0, stream,
                       keys, counts, cand);
    hipLaunchKernelGGL(topk_stage_b, dim3(16), dim3(64), 0, stream,
                       cms, cand, out_off, out_vals, out_valid,
                       ws_cx, ws_cy, ws_v);
    hipLaunchKernelGGL(crop_kernel, dim3(12800), dim3(256), 0, stream,
                       full, ws_cx, ws_cy, ws_v, out_crops);
}